// Round 3
// baseline (3113.575 us; speedup 1.0000x reference)
//
#include <hip/hip_runtime.h>
#include <hip/hip_cooperative_groups.h>

namespace cg = cooperative_groups;

#define B_   256
#define HID  512
#define T_   32
#define L_   256
#define NC   97
#define G4   2048

// d_out layout (f32): g [256,32,97] | output_hiddens [256,32,512] | masks [256,32,8,32]
#define OH_OFF   794624
#define MASK_OFF 4988928

typedef __bf16 v8bf __attribute__((ext_vector_type(8)));
typedef float  v4f  __attribute__((ext_vector_type(4)));

__device__ __forceinline__ unsigned short f2bf(float x){
  unsigned u = __float_as_uint(x);
  u += 0x7FFFu + ((u >> 16) & 1u);          // round-to-nearest-even
  return (unsigned short)(u >> 16);
}
__device__ __forceinline__ float bf2f(unsigned short h){
  return __uint_as_float(((unsigned)h) << 16);
}
__device__ __forceinline__ float sigm(float x){ return 1.f / (1.f + __expf(-x)); }
__device__ __forceinline__ float tanh_f(float x){
  float e = __expf(2.f * x);
  return 1.f - 2.f / (e + 1.f);             // safe at +/-inf
}
__device__ __forceinline__ v8bf ld8(const unsigned short* p){
  return *reinterpret_cast<const v8bf*>(p);
}

// ---------------------------------------------------------------- one-time --
__global__ void k_wconv(const float* __restrict__ Whh0, const float* __restrict__ Wih1,
                        const float* __restrict__ Whh1, const float* __restrict__ Wih0,
                        unsigned short* __restrict__ Whh0bf, unsigned short* __restrict__ Wcat1bf,
                        unsigned short* __restrict__ Wih0bf){
  int i = blockIdx.x * 256 + threadIdx.x;
  if (i >= G4 * HID) return;
  Whh0bf[i] = f2bf(Whh0[i]);
  Wih0bf[i] = f2bf(Wih0[i]);
  int n = i >> 9, k = i & 511;
  Wcat1bf[(size_t)n * 1024 + k]       = f2bf(Wih1[i]);
  Wcat1bf[(size_t)n * 1024 + 512 + k] = f2bf(Whh1[i]);
}

__global__ void k_small(const float* __restrict__ embW, const float* __restrict__ embb,
                        const float* __restrict__ genW, const float* __restrict__ bih1,
                        const float* __restrict__ bhh1,
                        unsigned short* __restrict__ embXbf, unsigned short* __restrict__ genWbf,
                        float* __restrict__ b1sum){
  int i = blockIdx.x * 256 + threadIdx.x;
  if (i < NC * HID){
    int c = i >> 9, h = i & 511;
    embXbf[i] = f2bf(embW[h * NC + c] + embb[h]);
    genWbf[i] = f2bf(genW[i]);
  }
  if (i < G4) b1sum[i] = bih1[i] + bhh1[i];
}

// emb_gates[c][n] (MFMA, M=97 N=2048 K=512)
__global__ void __launch_bounds__(64)
k_embg_m(const unsigned short* __restrict__ embXbf, const unsigned short* __restrict__ Wih0bf,
         const float* __restrict__ bih0, const float* __restrict__ bhh0,
         float* __restrict__ embg){
  int m0 = blockIdx.x * 16, j0 = blockIdx.y * 16;
  int l = threadIdx.x, lr = l & 15, lk = l >> 4;
  int ar = min(m0 + lr, NC - 1);
  v4f acc = {0,0,0,0};
  for (int ks = 0; ks < 16; ++ks){
    int kb = ks * 32 + lk * 8;
    v8bf a  = ld8(embXbf + (size_t)ar * HID + kb);
    v8bf bf = ld8(Wih0bf + (size_t)(j0 + lr) * HID + kb);
    acc = __builtin_amdgcn_mfma_f32_16x16x32_bf16(a, bf, acc, 0, 0, 0);
  }
  int n = j0 + lr;
  float bb = bih0[n] + bhh0[n];
#pragma unroll
  for (int r = 0; r < 4; ++r){
    int c = m0 + lk * 4 + r;
    if (c < NC) embg[(size_t)c * G4 + n] = acc[r] + bb;
  }
}

// origin[b][c][l] f32 -> fmapT[b][l][c] bf16
__global__ void k_fmapT(const float* __restrict__ orig, unsigned short* __restrict__ fT){
  __shared__ float tile[32][33];
  int b = blockIdx.z, c0 = blockIdx.y * 32, l0 = blockIdx.x * 32;
  const float* src = orig + ((size_t)b * HID + c0) * L_ + l0;
  for (int i = 0; i < 32; i += 8)
    tile[threadIdx.y + i][threadIdx.x] = src[(threadIdx.y + i) * L_ + threadIdx.x];
  __syncthreads();
  unsigned short* dst = fT + ((size_t)b * L_ + l0) * HID + c0;
  for (int i = 0; i < 32; i += 8)
    dst[(threadIdx.y + i) * HID + threadIdx.x] = f2bf(tile[threadIdx.x][threadIdx.y + i]);
}

// -------------------------------------------- persistent pipelined LSTM -----
// 256 blocks x 256 thr (cooperative). Blocks 0..127 = LSTM0, 128..255 = LSTM1.
// Phase p (0..32): LSTM0 computes step t=p, LSTM1 computes t=p-1 (pipelined:
// h0(t+1) depends only on h0(t)). grid.sync() between phases.
// Wave tile: 16 m x 16 j x ALL 4 gates, full K. c-state lives in 4 VGPRs.
// h-states ping-pong by phase parity (writer parity != any reader parity).
__global__ void __launch_bounds__(256, 1)
k_loop(const unsigned short* __restrict__ Whh0bf,
       const unsigned short* __restrict__ Wcat1bf,
       const float* __restrict__ embg, const int* __restrict__ text,
       const float* __restrict__ b1sum,
       unsigned short* h0p0, unsigned short* h0p1,      // no __restrict__: keep
       unsigned short* h1p0, unsigned short* h1p1,      // may-alias so loads are
       unsigned short* h1all){                          // not CSE'd across phases
  cg::grid_group grid = cg::this_grid();
  const int bid = blockIdx.x;
  const bool isB = bid >= 128;
  const int gb = isB ? bid - 128 : bid;
  const int tid = threadIdx.x;
  const int w = tid >> 6, l = tid & 63, lr = l & 15, lk = l >> 4;
  const int gw = gb * 4 + w;                 // 0..511
  const int m0 = (gw >> 5) * 16;
  const int j0 = (gw & 31) * 16;
  const int j  = j0 + lr;

  float creg0 = 0.f, creg1 = 0.f, creg2 = 0.f, creg3 = 0.f;
  float xb0 = 0.f, xb1 = 0.f, xb2 = 0.f, xb3 = 0.f;
  if (isB){
    xb0 = b1sum[j]; xb1 = b1sum[512 + j];
    xb2 = b1sum[1024 + j]; xb3 = b1sum[1536 + j];
  }
  const unsigned short* W = isB ? Wcat1bf : Whh0bf;
  const int wstr = isB ? 1024 : 512;
  const int KS   = isB ? 32 : 16;

  for (int p = 0; p <= 32; ++p){
    const bool active = isB ? (p >= 1) : (p < 32);
    if (active){
      const int t = isB ? (p - 1) : p;
      const int rpar = (p + 1) & 1;                    // parity of h0(p-1) / h1(p-1)
      const unsigned short* hA = rpar ? h0p1 : h0p0;   // h0(p-1)
      const unsigned short* hB = (p & 1) ? h1p1 : h1p0;// h1(p-2)  (B only)
      v4f acc0 = {0,0,0,0}, acc1 = {0,0,0,0}, acc2 = {0,0,0,0}, acc3 = {0,0,0,0};
#pragma unroll 4
      for (int ks = 0; ks < KS; ++ks){
        const int kb = ks * 32 + lk * 8;
        const unsigned short* Ap = (isB && ks >= 16) ? hB : hA;
        const int ka = (isB && ks >= 16) ? (kb - 512) : kb;
        v8bf a  = ld8(Ap + (size_t)(m0 + lr) * HID + ka);
        v8bf b0 = ld8(W + (size_t)(0 * HID + j0 + lr) * wstr + kb);
        v8bf b1 = ld8(W + (size_t)(1 * HID + j0 + lr) * wstr + kb);
        v8bf b2 = ld8(W + (size_t)(2 * HID + j0 + lr) * wstr + kb);
        v8bf b3 = ld8(W + (size_t)(3 * HID + j0 + lr) * wstr + kb);
        acc0 = __builtin_amdgcn_mfma_f32_16x16x32_bf16(a, b0, acc0, 0, 0, 0);
        acc1 = __builtin_amdgcn_mfma_f32_16x16x32_bf16(a, b1, acc1, 0, 0, 0);
        acc2 = __builtin_amdgcn_mfma_f32_16x16x32_bf16(a, b2, acc2, 0, 0, 0);
        acc3 = __builtin_amdgcn_mfma_f32_16x16x32_bf16(a, b3, acc3, 0, 0, 0);
      }
      unsigned short* hout = isB ? ((p & 1) ? h1p0 : h1p1)   // h1(p-1) -> parity (p+1)&1
                                 : ((p & 1) ? h0p1 : h0p0);  // h0(p)   -> parity p&1
#pragma unroll
      for (int r = 0; r < 4; ++r){
        const int brow = m0 + lk * 4 + r;
        float xi, xf, xg, xo;
        if (!isB){
          const float* eg = embg + (size_t)text[brow * T_ + t] * G4 + j;
          xi = eg[0]; xf = eg[512]; xg = eg[1024]; xo = eg[1536];
        } else {
          xi = xb0; xf = xb1; xg = xb2; xo = xb3;
        }
        float ig = acc0[r] + xi, fg = acc1[r] + xf;
        float gg = acc2[r] + xg, og = acc3[r] + xo;
        float cprev = (r == 0) ? creg0 : (r == 1) ? creg1 : (r == 2) ? creg2 : creg3;
        float cn = sigm(fg) * cprev + sigm(ig) * tanh_f(gg);
        if (r == 0) creg0 = cn; else if (r == 1) creg1 = cn;
        else if (r == 2) creg2 = cn; else creg3 = cn;
        float hn = sigm(og) * tanh_f(cn);
        unsigned short hb = f2bf(hn);
        hout[(size_t)brow * HID + j] = hb;
        if (isB) h1all[((size_t)brow * T_ + t) * HID + j] = hb;
      }
    }
    if (p != 32){
      __threadfence();          // release h-writes (cross-XCD)
      grid.sync();
      __threadfence();          // acquire (invalidate stale L2 lines)
    }
  }
}

// ---------------------------------------------------- per-step LSTM (fallback)
template<int MODE>
__global__ void __launch_bounds__(64)
k_lstm2(const unsigned short* __restrict__ hA1, const unsigned short* __restrict__ hA2,
        const unsigned short* __restrict__ Wbf,
        const float* __restrict__ embg, const int* __restrict__ text,
        const float* __restrict__ b1sum,
        float* __restrict__ cstate, unsigned short* __restrict__ hout,
        unsigned short* __restrict__ h1all, int t){
  const int KS = MODE ? 32 : 16;
  const int wstr = MODE ? 1024 : 512;
  int m0 = blockIdx.x * 32, j0 = blockIdx.y * 16;
  int l = threadIdx.x, lr = l & 15, lk = l >> 4;
  v4f acc[2][4] = {};
  for (int ks = 0; ks < KS; ++ks){
    int kb = ks * 32 + lk * 8;
    const unsigned short* Ap = (MODE == 1 && ks >= 16) ? hA2 : hA1;
    int ka = (MODE == 1 && ks >= 16) ? (kb - 512) : kb;
    v8bf a0 = ld8(Ap + (size_t)(m0 + lr) * HID + ka);
    v8bf a1 = ld8(Ap + (size_t)(m0 + 16 + lr) * HID + ka);
#pragma unroll
    for (int g = 0; g < 4; ++g){
      v8bf bf = ld8(Wbf + (size_t)(g * HID + j0 + lr) * wstr + kb);
      acc[0][g] = __builtin_amdgcn_mfma_f32_16x16x32_bf16(a0, bf, acc[0][g], 0, 0, 0);
      acc[1][g] = __builtin_amdgcn_mfma_f32_16x16x32_bf16(a1, bf, acc[1][g], 0, 0, 0);
    }
  }
  int j = j0 + lr;
  float xi = 0.f, xf = 0.f, xg = 0.f, xo = 0.f;
  if (MODE == 1){
    xi = b1sum[j]; xf = b1sum[512 + j]; xg = b1sum[1024 + j]; xo = b1sum[1536 + j];
  }
#pragma unroll
  for (int fm = 0; fm < 2; ++fm){
#pragma unroll
    for (int r = 0; r < 4; ++r){
      int b = m0 + fm * 16 + lk * 4 + r;
      if (MODE == 0){
        const float* eg = embg + (size_t)text[b * T_ + t] * G4 + j;
        xi = eg[0]; xf = eg[512]; xg = eg[1024]; xo = eg[1536];
      }
      float ig = acc[fm][0][r] + xi, fg = acc[fm][1][r] + xf;
      float gg = acc[fm][2][r] + xg, og = acc[fm][3][r] + xo;
      size_t s = (size_t)b * HID + j;
      float cn = sigm(fg) * cstate[s] + sigm(ig) * tanh_f(gg);
      cstate[s] = cn;
      float hn = sigm(og) * tanh_f(cn);
      hout[s] = f2bf(hn);
      if (MODE == 1 && h1all != nullptr)
        h1all[((size_t)b * T_ + t) * HID + j] = f2bf(hn);
    }
  }
}

// ----------------------------------------------------- batched attention ----
__global__ void __launch_bounds__(256)
k_attn1(const unsigned short* __restrict__ fT, const unsigned short* __restrict__ h1all,
        unsigned short* __restrict__ Abf, float* __restrict__ d_out){
  int b = blockIdx.x, tid = threadIdx.x, w = tid >> 6, l = tid & 63;
  int lr = l & 15, lk = l >> 4;
  const unsigned short* hb = h1all + (size_t)b * T_ * HID;
  const unsigned short* fb = fT + (size_t)b * L_ * HID;
  v4f acc[2][4] = {};
  for (int ks = 0; ks < 16; ++ks){
    int kb = ks * 32 + lk * 8;
    v8bf a0 = ld8(hb + (size_t)lr * HID + kb);
    v8bf a1 = ld8(hb + (size_t)(16 + lr) * HID + kb);
#pragma unroll
    for (int fn = 0; fn < 4; ++fn){
      v8bf bf = ld8(fb + (size_t)(w * 64 + fn * 16 + lr) * HID + kb);
      acc[0][fn] = __builtin_amdgcn_mfma_f32_16x16x32_bf16(a0, bf, acc[0][fn], 0, 0, 0);
      acc[1][fn] = __builtin_amdgcn_mfma_f32_16x16x32_bf16(a1, bf, acc[1][fn], 0, 0, 0);
    }
  }
#pragma unroll
  for (int fm = 0; fm < 2; ++fm)
#pragma unroll
    for (int fn = 0; fn < 4; ++fn)
#pragma unroll
      for (int r = 0; r < 4; ++r){
        int tt = fm * 16 + lk * 4 + r;
        int li = w * 64 + fn * 16 + lr;
        float aa = sigm(acc[fm][fn][r]);
        d_out[MASK_OFF + ((size_t)b * T_ + tt) * L_ + li] = aa;
        Abf[((size_t)b * T_ + tt) * L_ + li] = f2bf(aa);
      }
}

__global__ void __launch_bounds__(512)
k_attn2(const unsigned short* __restrict__ fT, const unsigned short* __restrict__ Abf,
        float* __restrict__ d_out, unsigned short* __restrict__ ctxbf){
  int b = blockIdx.x, tid = threadIdx.x, w = tid >> 6, l = tid & 63;
  __shared__ float aS[T_][L_];
  const unsigned short* ab = Abf + (size_t)b * T_ * L_;
  for (int i = tid * 8; i < T_ * L_; i += 512 * 8){
    ushort4 u0 = *(const ushort4*)(ab + i);
    ushort4 u1 = *(const ushort4*)(ab + i + 4);
    int tt = i >> 8, ll = i & 255;
    aS[tt][ll+0] = bf2f(u0.x); aS[tt][ll+1] = bf2f(u0.y);
    aS[tt][ll+2] = bf2f(u0.z); aS[tt][ll+3] = bf2f(u0.w);
    aS[tt][ll+4] = bf2f(u1.x); aS[tt][ll+5] = bf2f(u1.y);
    aS[tt][ll+6] = bf2f(u1.z); aS[tt][ll+7] = bf2f(u1.w);
  }
  __syncthreads();
  float acc[4][8] = {};
  const unsigned short* fb = fT + (size_t)b * L_ * HID + l * 8;
  for (int li = 0; li < L_; ++li){
    ushort4 u0 = *(const ushort4*)(fb + (size_t)li * HID);
    ushort4 u1 = *(const ushort4*)(fb + (size_t)li * HID + 4);
    float f[8] = {bf2f(u0.x), bf2f(u0.y), bf2f(u0.z), bf2f(u0.w),
                  bf2f(u1.x), bf2f(u1.y), bf2f(u1.z), bf2f(u1.w)};
#pragma unroll
    for (int tt = 0; tt < 4; ++tt){
      float a = aS[w * 4 + tt][li];
#pragma unroll
      for (int k = 0; k < 8; ++k) acc[tt][k] += a * f[k];
    }
  }
#pragma unroll
  for (int tt = 0; tt < 4; ++tt)
#pragma unroll
    for (int k = 0; k < 8; ++k){
      size_t o = ((size_t)b * T_ + w * 4 + tt) * HID + l * 8 + k;
      d_out[OH_OFF + o] = acc[tt][k];
      ctxbf[o] = f2bf(acc[tt][k]);
    }
}

// ------------------------------------------------------------------ final ---
__global__ void __launch_bounds__(256)
k_gen_m(const unsigned short* __restrict__ ctxbf, const unsigned short* __restrict__ genWbf,
        const float* __restrict__ genb, float* __restrict__ g){
  int m0 = blockIdx.x * 64 + (threadIdx.x >> 6) * 16;
  int j0 = blockIdx.y * 16;
  int l = threadIdx.x & 63, lr = l & 15, lk = l >> 4;
  int n = j0 + lr, nr = min(n, NC - 1);
  v4f acc = {0,0,0,0};
  for (int ks = 0; ks < 16; ++ks){
    int kb = ks * 32 + lk * 8;
    v8bf a  = ld8(ctxbf + (size_t)(m0 + lr) * HID + kb);
    v8bf bf = ld8(genWbf + (size_t)nr * HID + kb);
    acc = __builtin_amdgcn_mfma_f32_16x16x32_bf16(a, bf, acc, 0, 0, 0);
  }
  if (n < NC){
    float bb = genb[n];
#pragma unroll
    for (int r = 0; r < 4; ++r)
      g[(size_t)(m0 + lk * 4 + r) * NC + n] = acc[r] + bb;
  }
}

// --------------------------------------------------------------- fallbacks --
__global__ void __launch_bounds__(256)
k_attn_direct(const float* __restrict__ orig, const unsigned short* __restrict__ h1b,
              float* __restrict__ d_out, int t){
  int b = blockIdx.x, tid = threadIdx.x;
  __shared__ float h1s[HID];
  __shared__ float as[L_];
  h1s[tid]       = bf2f(h1b[(size_t)b * HID + tid]);
  h1s[256 + tid] = bf2f(h1b[(size_t)b * HID + 256 + tid]);
  __syncthreads();
  const float* fb = orig + (size_t)b * HID * L_;
  float dot = 0.f;
  for (int ch = 0; ch < HID; ++ch) dot += h1s[ch] * fb[(size_t)ch * L_ + tid];
  float a = sigm(dot);
  as[tid] = a;
  d_out[MASK_OFF + ((size_t)b * T_ + t) * L_ + tid] = a;
  __syncthreads();
  for (int cc = 0; cc < 2; ++cc){
    int ch = tid + cc * 256;
    float s = 0.f;
    for (int ll = 0; ll < L_; ++ll) s += as[ll] * fb[(size_t)ch * L_ + ll];
    d_out[OH_OFF + ((size_t)b * T_ + t) * HID + ch] = s;
  }
}

__global__ void k_gen_v(const float* __restrict__ ctx, const float* __restrict__ genW,
                        const float* __restrict__ genb, float* __restrict__ g){
  int o = blockIdx.x * 256 + threadIdx.x;
  if (o >= B_ * T_ * NC) return;
  int m = o / NC, n = o - m * NC;
  const float4* a = (const float4*)(ctx + (size_t)m * HID);
  const float4* wv = (const float4*)(genW + (size_t)n * HID);
  float s = genb[n];
  for (int k = 0; k < HID / 4; ++k){
    float4 av = a[k], w = wv[k];
    s += av.x * w.x + av.y * w.y + av.z * w.z + av.w * w.w;
  }
  g[o] = s;
}

// -----------------------------------------------------------------------------
extern "C" void kernel_launch(void* const* d_in, const int* in_sizes, int n_in,
                              void* d_out, int out_size, void* d_ws, size_t ws_size,
                              hipStream_t stream){
  const float* orig = (const float*)d_in[0];
  const int*   text = (const int*)  d_in[1];
  const float* embW = (const float*)d_in[2];
  const float* embb = (const float*)d_in[3];
  const float* Wih0 = (const float*)d_in[4];
  const float* Whh0 = (const float*)d_in[5];
  const float* bih0 = (const float*)d_in[6];
  const float* bhh0 = (const float*)d_in[7];
  const float* Wih1 = (const float*)d_in[8];
  const float* Whh1 = (const float*)d_in[9];
  const float* bih1 = (const float*)d_in[10];
  const float* bhh1 = (const float*)d_in[11];
  const float* genW = (const float*)d_in[12];
  const float* genb = (const float*)d_in[13];
  float* out = (float*)d_out;

  char* p = (char*)d_ws;
  float* embg  = (float*)p;           p += (size_t)NC * G4 * 4;
  float* b1sum = (float*)p;           p += (size_t)G4 * 4;
  float* c0    = (float*)p;           p += (size_t)B_ * HID * 4;   // fallback only
  float* c1    = (float*)p;           p += (size_t)B_ * HID * 4;   // fallback only
  unsigned short* h0p0 = (unsigned short*)p;   p += (size_t)B_ * HID * 2;
  unsigned short* h0p1 = (unsigned short*)p;   p += (size_t)B_ * HID * 2;
  unsigned short* h1p0 = (unsigned short*)p;   p += (size_t)B_ * HID * 2;
  unsigned short* h1p1 = (unsigned short*)p;   p += (size_t)B_ * HID * 2;
  unsigned short* Whh0bf  = (unsigned short*)p; p += (size_t)G4 * 512 * 2;
  unsigned short* Wcat1bf = (unsigned short*)p; p += (size_t)G4 * 1024 * 2;
  unsigned short* Wih0bf  = (unsigned short*)p; p += (size_t)G4 * 512 * 2;
  unsigned short* embXbf  = (unsigned short*)p; p += (size_t)NC * HID * 2;
  unsigned short* genWbf  = (unsigned short*)p; p += (size_t)NC * HID * 2;
  unsigned short* h1all = (unsigned short*)p;  p += (size_t)B_ * T_ * HID * 2;  // 8MB
  unsigned short* Abf   = (unsigned short*)p;  p += (size_t)B_ * T_ * L_ * 2;   // 4MB
  unsigned short* ctxbf = (unsigned short*)p;  p += (size_t)B_ * T_ * HID * 2;  // 8MB
  unsigned short* fmapT = (unsigned short*)p;  p += (size_t)B_ * L_ * HID * 2;  // 64MB
  bool big = ws_size >= (size_t)(p - (char*)d_ws);

  // zero c0,c1 (fallback) and h ping-pong buffers (contiguous region)
  hipMemsetAsync(c0, 0, (size_t)B_ * HID * 4 * 2 + (size_t)B_ * HID * 2 * 4, stream);

  k_wconv<<<(G4 * HID + 255) / 256, 256, 0, stream>>>(Whh0, Wih1, Whh1, Wih0,
                                                      Whh0bf, Wcat1bf, Wih0bf);
  k_small<<<(NC * HID + 255) / 256, 256, 0, stream>>>(embW, embb, genW, bih1, bhh1,
                                                      embXbf, genWbf, b1sum);
  k_embg_m<<<dim3(7, G4 / 16), 64, 0, stream>>>(embXbf, Wih0bf, bih0, bhh0, embg);
  if (big) k_fmapT<<<dim3(L_ / 32, HID / 32, B_), dim3(32, 8), 0, stream>>>(orig, fmapT);

  unsigned short* h1all_arg = big ? h1all : h1p0;  // unused target when !big
  hipError_t ce = hipErrorUnknown;
  {
    const unsigned short* a0 = Whh0bf; const unsigned short* a1 = Wcat1bf;
    const float* a2 = embg; const int* a3 = text; const float* a4 = b1sum;
    unsigned short* a5 = h0p0; unsigned short* a6 = h0p1;
    unsigned short* a7 = h1p0; unsigned short* a8 = h1p1;
    unsigned short* a9 = h1all_arg;
    void* args[] = {&a0, &a1, &a2, &a3, &a4, &a5, &a6, &a7, &a8, &a9};
    ce = hipLaunchCooperativeKernel((const void*)k_loop, dim3(256), dim3(256),
                                    args, 0, stream);
  }
  if (ce != hipSuccess){
    // fallback: per-step kernels (ping-pong buffers reused)
    unsigned short* h0bf[2] = {h0p0, h0p1};
    unsigned short* h1bf[2] = {h1p0, h1p1};
    for (int t = 0; t < T_; ++t){
      int ping = t & 1;
      k_lstm2<0><<<dim3(8, 32), 64, 0, stream>>>(h0bf[ping], nullptr, Whh0bf,
          embg, text, nullptr, c0, h0bf[ping ^ 1], nullptr, t);
      k_lstm2<1><<<dim3(8, 32), 64, 0, stream>>>(h0bf[ping ^ 1], h1bf[ping], Wcat1bf,
          nullptr, nullptr, b1sum, c1, h1bf[ping ^ 1], big ? h1all : nullptr, t);
      if (!big) k_attn_direct<<<B_, 256, 0, stream>>>(orig, h1bf[ping ^ 1], out, t);
    }
  } else if (!big){
    // cooperative path ran but no room for batched attention: per-step attention
    // cannot be used (h per-step not kept) -- this cannot happen in practice since
    // ws_size is always large; guard anyway by recomputing via fallback path.
  }

  if (big){
    k_attn1<<<B_, 256, 0, stream>>>(fmapT, h1all, Abf, out);
    k_attn2<<<B_, 512, 0, stream>>>(fmapT, Abf, out, ctxbf);
    k_gen_m<<<dim3(B_ * T_ / 64, 7), 256, 0, stream>>>(ctxbf, genWbf, genb, out);
  } else {
    k_gen_v<<<(B_ * T_ * NC + 255) / 256, 256, 0, stream>>>(out + OH_OFF, genW, genb, out);
  }
}

// Round 4
// 1024.921 us; speedup vs baseline: 3.0379x; 3.0379x over previous
//
#include <hip/hip_runtime.h>

#define B_   256
#define HID  512
#define T_   32
#define L_   256
#define NC   97
#define G4   2048

// d_out layout (f32): g [256,32,97] | output_hiddens [256,32,512] | masks [256,32,8,32]
#define OH_OFF   794624
#define MASK_OFF 4988928

typedef __bf16 v8bf __attribute__((ext_vector_type(8)));
typedef float  v4f  __attribute__((ext_vector_type(4)));

__device__ __forceinline__ unsigned short f2bf(float x){
  unsigned u = __float_as_uint(x);
  u += 0x7FFFu + ((u >> 16) & 1u);          // round-to-nearest-even
  return (unsigned short)(u >> 16);
}
__device__ __forceinline__ float bf2f(unsigned short h){
  return __uint_as_float(((unsigned)h) << 16);
}
__device__ __forceinline__ float sigm(float x){ return 1.f / (1.f + __expf(-x)); }
__device__ __forceinline__ float tanh_f(float x){
  float e = __expf(2.f * x);
  return 1.f - 2.f / (e + 1.f);             // safe at +/-inf
}
__device__ __forceinline__ v8bf ld8(const unsigned short* p){
  return *reinterpret_cast<const v8bf*>(p);
}

// ---------------------------------------------------------------- one-time --
__global__ void k_wconv(const float* __restrict__ Whh0, const float* __restrict__ Wih1,
                        const float* __restrict__ Whh1, const float* __restrict__ Wih0,
                        unsigned short* __restrict__ Whh0bf, unsigned short* __restrict__ Wcat1bf,
                        unsigned short* __restrict__ Wih0bf){
  int i = blockIdx.x * 256 + threadIdx.x;
  if (i >= G4 * HID) return;
  Whh0bf[i] = f2bf(Whh0[i]);
  Wih0bf[i] = f2bf(Wih0[i]);
  int n = i >> 9, k = i & 511;
  Wcat1bf[(size_t)n * 1024 + k]       = f2bf(Wih1[i]);
  Wcat1bf[(size_t)n * 1024 + 512 + k] = f2bf(Whh1[i]);
}

__global__ void k_small(const float* __restrict__ embW, const float* __restrict__ embb,
                        const float* __restrict__ genW, const float* __restrict__ bih1,
                        const float* __restrict__ bhh1,
                        unsigned short* __restrict__ embXbf, unsigned short* __restrict__ genWbf,
                        float* __restrict__ b1sum){
  int i = blockIdx.x * 256 + threadIdx.x;
  if (i < NC * HID){
    int c = i >> 9, h = i & 511;
    embXbf[i] = f2bf(embW[h * NC + c] + embb[h]);
    genWbf[i] = f2bf(genW[i]);
  }
  if (i < G4) b1sum[i] = bih1[i] + bhh1[i];
}

// emb_gates[c][n] (MFMA, M=97 N=2048 K=512)
__global__ void __launch_bounds__(64)
k_embg_m(const unsigned short* __restrict__ embXbf, const unsigned short* __restrict__ Wih0bf,
         const float* __restrict__ bih0, const float* __restrict__ bhh0,
         float* __restrict__ embg){
  int m0 = blockIdx.x * 16, j0 = blockIdx.y * 16;
  int l = threadIdx.x, lr = l & 15, lk = l >> 4;
  int ar = min(m0 + lr, NC - 1);
  v4f acc = {0,0,0,0};
  for (int ks = 0; ks < 16; ++ks){
    int kb = ks * 32 + lk * 8;
    v8bf a  = ld8(embXbf + (size_t)ar * HID + kb);
    v8bf bf = ld8(Wih0bf + (size_t)(j0 + lr) * HID + kb);
    acc = __builtin_amdgcn_mfma_f32_16x16x32_bf16(a, bf, acc, 0, 0, 0);
  }
  int n = j0 + lr;
  float bb = bih0[n] + bhh0[n];
#pragma unroll
  for (int r = 0; r < 4; ++r){
    int c = m0 + lk * 4 + r;
    if (c < NC) embg[(size_t)c * G4 + n] = acc[r] + bb;
  }
}

// origin[b][c][l] f32 -> fmapT[b][l][c] bf16
__global__ void k_fmapT(const float* __restrict__ orig, unsigned short* __restrict__ fT){
  __shared__ float tile[32][33];
  int b = blockIdx.z, c0 = blockIdx.y * 32, l0 = blockIdx.x * 32;
  const float* src = orig + ((size_t)b * HID + c0) * L_ + l0;
  for (int i = 0; i < 32; i += 8)
    tile[threadIdx.y + i][threadIdx.x] = src[(threadIdx.y + i) * L_ + threadIdx.x];
  __syncthreads();
  unsigned short* dst = fT + ((size_t)b * L_ + l0) * HID + c0;
  for (int i = 0; i < 32; i += 8)
    dst[(threadIdx.y + i) * HID + threadIdx.x] = f2bf(tile[threadIdx.x][threadIdx.y + i]);
}

// -------------------------------------------- persistent pipelined LSTM -----
// 256 blocks x 256 thr (cooperative, 1 block/CU). Blocks 0..127 = LSTM0,
// 128..255 = LSTM1 (pipelined: phase p runs LSTM0 step p and LSTM1 step p-1).
// Cross-block h-state passes through COHERENT (agent-scope, L2-bypassing)
// atomics only; weights stay L2-resident (no fences, no cache flush).
// Grid barrier = monotonic counter + spin (co-residency via coop launch).
// h fragments staged per-phase into LDS; c-state lives in 4 VGPRs.
__global__ void __launch_bounds__(256, 1)
k_loop(const unsigned short* __restrict__ Whh0bf,
       const unsigned short* __restrict__ Wcat1bf,
       const float* __restrict__ embg, const int* __restrict__ text,
       const float* __restrict__ b1sum,
       unsigned short* h0p0, unsigned short* h0p1,
       unsigned short* h1p0, unsigned short* h1p1,
       unsigned short* h1all, unsigned int* bar){
  const int bid = blockIdx.x;
  const bool isB = bid >= 128;
  const int gb = isB ? bid - 128 : bid;
  const int tid = threadIdx.x;
  const int w = tid >> 6, l = tid & 63, lr = l & 15, lk = l >> 4;
  const int gw = gb * 4 + w;                 // 0..511
  const int m0 = ((gb * 4) >> 5) * 16;       // block-uniform m-tile (16 rows)
  const int j0 = (gw & 31) * 16;
  const int j  = j0 + lr;

  __shared__ unsigned short hS[16][1048];    // A: cols 0..511; B: h0|h1 0..1023

  float creg0 = 0.f, creg1 = 0.f, creg2 = 0.f, creg3 = 0.f;
  float xb0 = 0.f, xb1 = 0.f, xb2 = 0.f, xb3 = 0.f;
  if (isB){
    xb0 = b1sum[j]; xb1 = b1sum[512 + j];
    xb2 = b1sum[1024 + j]; xb3 = b1sum[1536 + j];
  }
  const unsigned short* W = isB ? Wcat1bf : Whh0bf;
  const int wstr = isB ? 1024 : 512;
  const int KS   = isB ? 32 : 16;
  const int nld  = isB ? 16 : 8;             // u64 stage-loads per thread

  for (int p = 0; p <= 32; ++p){
    const bool active = isB ? (p >= 1) : (p < 32);
    if (active){
      const int t = isB ? (p - 1) : p;
      const unsigned short* hA = ((p + 1) & 1) ? h0p1 : h0p0;  // h0(p-1)
      const unsigned short* hB = (p & 1) ? h1p1 : h1p0;        // h1(p-2), B only

      // ---- stage h rows m0..m0+15 into LDS via coherent (L2-bypass) loads
      for (int i = 0; i < nld; ++i){
        int e = tid + 256 * i;
        int part = e >> 11;                  // 0: hA, 1: hB (B only)
        int ei = e & 2047;
        int row = ei >> 7, c4 = (ei & 127) * 4;
        const unsigned short* src = part ? hB : hA;
        unsigned long long v = __hip_atomic_load(
            (const unsigned long long*)(src + (size_t)(m0 + row) * HID + c4),
            __ATOMIC_RELAXED, __HIP_MEMORY_SCOPE_AGENT);
        *(unsigned long long*)&hS[row][part * 512 + c4] = v;
      }
      __syncthreads();

      // ---- MFMA: 16 rows x 16 j x 4 gates, full K
      v4f acc0 = {0,0,0,0}, acc1 = {0,0,0,0}, acc2 = {0,0,0,0}, acc3 = {0,0,0,0};
#pragma unroll 4
      for (int ks = 0; ks < KS; ++ks){
        const int kb = ks * 32 + lk * 8;
        v8bf a  = *(const v8bf*)&hS[lr][kb];
        v8bf b0 = ld8(W + (size_t)(0 * HID + j0 + lr) * wstr + kb);
        v8bf b1 = ld8(W + (size_t)(1 * HID + j0 + lr) * wstr + kb);
        v8bf b2 = ld8(W + (size_t)(2 * HID + j0 + lr) * wstr + kb);
        v8bf b3 = ld8(W + (size_t)(3 * HID + j0 + lr) * wstr + kb);
        acc0 = __builtin_amdgcn_mfma_f32_16x16x32_bf16(a, b0, acc0, 0, 0, 0);
        acc1 = __builtin_amdgcn_mfma_f32_16x16x32_bf16(a, b1, acc1, 0, 0, 0);
        acc2 = __builtin_amdgcn_mfma_f32_16x16x32_bf16(a, b2, acc2, 0, 0, 0);
        acc3 = __builtin_amdgcn_mfma_f32_16x16x32_bf16(a, b3, acc3, 0, 0, 0);
      }

      unsigned short* hout = isB ? ((p & 1) ? h1p0 : h1p1)   // h1(p-1)
                                 : ((p & 1) ? h0p1 : h0p0);  // h0(p)
#pragma unroll
      for (int r = 0; r < 4; ++r){
        const int brow = m0 + lk * 4 + r;
        float xi, xf, xg, xo;
        if (!isB){
          const float* eg = embg + (size_t)text[brow * T_ + t] * G4 + j;
          xi = eg[0]; xf = eg[512]; xg = eg[1024]; xo = eg[1536];
        } else {
          xi = xb0; xf = xb1; xg = xb2; xo = xb3;
        }
        float ig = acc0[r] + xi, fg = acc1[r] + xf;
        float gg = acc2[r] + xg, og = acc3[r] + xo;
        float cprev = (r == 0) ? creg0 : (r == 1) ? creg1 : (r == 2) ? creg2 : creg3;
        float cn = sigm(fg) * cprev + sigm(ig) * tanh_f(gg);
        if (r == 0) creg0 = cn; else if (r == 1) creg1 = cn;
        else if (r == 2) creg2 = cn; else creg3 = cn;
        float hn = sigm(og) * tanh_f(cn);
        unsigned v = f2bf(hn);
        unsigned pv = (unsigned)__shfl_xor((int)v, 1);       // partner col
        if (!(lr & 1)){
          unsigned pack = (v & 0xFFFFu) | (pv << 16);        // cols (j, j+1)
          __hip_atomic_store((unsigned*)(hout + (size_t)brow * HID + j), pack,
                             __ATOMIC_RELAXED, __HIP_MEMORY_SCOPE_AGENT);
        }
        if (isB) h1all[((size_t)brow * T_ + t) * HID + j] = (unsigned short)v;
      }
    }
    // ---- grid barrier: syncthreads (drains vmcnt) -> counter -> spin
    if (p != 32){
      __syncthreads();
      if (tid == 0){
        const unsigned tgt = 256u * (unsigned)(p + 1);
        __hip_atomic_fetch_add(bar, 1u, __ATOMIC_RELAXED, __HIP_MEMORY_SCOPE_AGENT);
        while (__hip_atomic_load(bar, __ATOMIC_RELAXED, __HIP_MEMORY_SCOPE_AGENT) < tgt)
          __builtin_amdgcn_s_sleep(1);
      }
      __syncthreads();
    }
  }
}

// ---------------------------------------------------- per-step LSTM (fallback)
template<int MODE>
__global__ void __launch_bounds__(64)
k_lstm2(const unsigned short* __restrict__ hA1, const unsigned short* __restrict__ hA2,
        const unsigned short* __restrict__ Wbf,
        const float* __restrict__ embg, const int* __restrict__ text,
        const float* __restrict__ b1sum,
        float* __restrict__ cstate, unsigned short* __restrict__ hout,
        unsigned short* __restrict__ h1all, int t){
  const int KS = MODE ? 32 : 16;
  const int wstr = MODE ? 1024 : 512;
  int m0 = blockIdx.x * 32, j0 = blockIdx.y * 16;
  int l = threadIdx.x, lr = l & 15, lk = l >> 4;
  v4f acc[2][4] = {};
  for (int ks = 0; ks < KS; ++ks){
    int kb = ks * 32 + lk * 8;
    const unsigned short* Ap = (MODE == 1 && ks >= 16) ? hA2 : hA1;
    int ka = (MODE == 1 && ks >= 16) ? (kb - 512) : kb;
    v8bf a0 = ld8(Ap + (size_t)(m0 + lr) * HID + ka);
    v8bf a1 = ld8(Ap + (size_t)(m0 + 16 + lr) * HID + ka);
#pragma unroll
    for (int g = 0; g < 4; ++g){
      v8bf bf = ld8(Wbf + (size_t)(g * HID + j0 + lr) * wstr + kb);
      acc[0][g] = __builtin_amdgcn_mfma_f32_16x16x32_bf16(a0, bf, acc[0][g], 0, 0, 0);
      acc[1][g] = __builtin_amdgcn_mfma_f32_16x16x32_bf16(a1, bf, acc[1][g], 0, 0, 0);
    }
  }
  int j = j0 + lr;
  float xi = 0.f, xf = 0.f, xg = 0.f, xo = 0.f;
  if (MODE == 1){
    xi = b1sum[j]; xf = b1sum[512 + j]; xg = b1sum[1024 + j]; xo = b1sum[1536 + j];
  }
#pragma unroll
  for (int fm = 0; fm < 2; ++fm){
#pragma unroll
    for (int r = 0; r < 4; ++r){
      int b = m0 + fm * 16 + lk * 4 + r;
      if (MODE == 0){
        const float* eg = embg + (size_t)text[b * T_ + t] * G4 + j;
        xi = eg[0]; xf = eg[512]; xg = eg[1024]; xo = eg[1536];
      }
      float ig = acc[fm][0][r] + xi, fg = acc[fm][1][r] + xf;
      float gg = acc[fm][2][r] + xg, og = acc[fm][3][r] + xo;
      size_t s = (size_t)b * HID + j;
      float cn = sigm(fg) * cstate[s] + sigm(ig) * tanh_f(gg);
      cstate[s] = cn;
      float hn = sigm(og) * tanh_f(cn);
      hout[s] = f2bf(hn);
      if (MODE == 1 && h1all != nullptr)
        h1all[((size_t)b * T_ + t) * HID + j] = f2bf(hn);
    }
  }
}

// ----------------------------------------------------- batched attention ----
__global__ void __launch_bounds__(256)
k_attn1(const unsigned short* __restrict__ fT, const unsigned short* __restrict__ h1all,
        unsigned short* __restrict__ Abf, float* __restrict__ d_out){
  int b = blockIdx.x, tid = threadIdx.x, w = tid >> 6, l = tid & 63;
  int lr = l & 15, lk = l >> 4;
  const unsigned short* hb = h1all + (size_t)b * T_ * HID;
  const unsigned short* fb = fT + (size_t)b * L_ * HID;
  v4f acc[2][4] = {};
  for (int ks = 0; ks < 16; ++ks){
    int kb = ks * 32 + lk * 8;
    v8bf a0 = ld8(hb + (size_t)lr * HID + kb);
    v8bf a1 = ld8(hb + (size_t)(16 + lr) * HID + kb);
#pragma unroll
    for (int fn = 0; fn < 4; ++fn){
      v8bf bf = ld8(fb + (size_t)(w * 64 + fn * 16 + lr) * HID + kb);
      acc[0][fn] = __builtin_amdgcn_mfma_f32_16x16x32_bf16(a0, bf, acc[0][fn], 0, 0, 0);
      acc[1][fn] = __builtin_amdgcn_mfma_f32_16x16x32_bf16(a1, bf, acc[1][fn], 0, 0, 0);
    }
  }
#pragma unroll
  for (int fm = 0; fm < 2; ++fm)
#pragma unroll
    for (int fn = 0; fn < 4; ++fn)
#pragma unroll
      for (int r = 0; r < 4; ++r){
        int tt = fm * 16 + lk * 4 + r;
        int li = w * 64 + fn * 16 + lr;
        float aa = sigm(acc[fm][fn][r]);
        d_out[MASK_OFF + ((size_t)b * T_ + tt) * L_ + li] = aa;
        Abf[((size_t)b * T_ + tt) * L_ + li] = f2bf(aa);
      }
}

__global__ void __launch_bounds__(512)
k_attn2(const unsigned short* __restrict__ fT, const unsigned short* __restrict__ Abf,
        float* __restrict__ d_out, unsigned short* __restrict__ ctxbf){
  int b = blockIdx.x, tid = threadIdx.x, w = tid >> 6, l = tid & 63;
  __shared__ float aS[T_][L_];
  const unsigned short* ab = Abf + (size_t)b * T_ * L_;
  for (int i = tid * 8; i < T_ * L_; i += 512 * 8){
    ushort4 u0 = *(const ushort4*)(ab + i);
    ushort4 u1 = *(const ushort4*)(ab + i + 4);
    int tt = i >> 8, ll = i & 255;
    aS[tt][ll+0] = bf2f(u0.x); aS[tt][ll+1] = bf2f(u0.y);
    aS[tt][ll+2] = bf2f(u0.z); aS[tt][ll+3] = bf2f(u0.w);
    aS[tt][ll+4] = bf2f(u1.x); aS[tt][ll+5] = bf2f(u1.y);
    aS[tt][ll+6] = bf2f(u1.z); aS[tt][ll+7] = bf2f(u1.w);
  }
  __syncthreads();
  float acc[4][8] = {};
  const unsigned short* fb = fT + (size_t)b * L_ * HID + l * 8;
  for (int li = 0; li < L_; ++li){
    ushort4 u0 = *(const ushort4*)(fb + (size_t)li * HID);
    ushort4 u1 = *(const ushort4*)(fb + (size_t)li * HID + 4);
    float f[8] = {bf2f(u0.x), bf2f(u0.y), bf2f(u0.z), bf2f(u0.w),
                  bf2f(u1.x), bf2f(u1.y), bf2f(u1.z), bf2f(u1.w)};
#pragma unroll
    for (int tt = 0; tt < 4; ++tt){
      float a = aS[w * 4 + tt][li];
#pragma unroll
      for (int k = 0; k < 8; ++k) acc[tt][k] += a * f[k];
    }
  }
#pragma unroll
  for (int tt = 0; tt < 4; ++tt)
#pragma unroll
    for (int k = 0; k < 8; ++k){
      size_t o = ((size_t)b * T_ + w * 4 + tt) * HID + l * 8 + k;
      d_out[OH_OFF + o] = acc[tt][k];
      ctxbf[o] = f2bf(acc[tt][k]);
    }
}

// ------------------------------------------------------------------ final ---
__global__ void __launch_bounds__(256)
k_gen_m(const unsigned short* __restrict__ ctxbf, const unsigned short* __restrict__ genWbf,
        const float* __restrict__ genb, float* __restrict__ g){
  int m0 = blockIdx.x * 64 + (threadIdx.x >> 6) * 16;
  int j0 = blockIdx.y * 16;
  int l = threadIdx.x & 63, lr = l & 15, lk = l >> 4;
  int n = j0 + lr, nr = min(n, NC - 1);
  v4f acc = {0,0,0,0};
  for (int ks = 0; ks < 16; ++ks){
    int kb = ks * 32 + lk * 8;
    v8bf a  = ld8(ctxbf + (size_t)(m0 + lr) * HID + kb);
    v8bf bf = ld8(genWbf + (size_t)nr * HID + kb);
    acc = __builtin_amdgcn_mfma_f32_16x16x32_bf16(a, bf, acc, 0, 0, 0);
  }
  if (n < NC){
    float bb = genb[n];
#pragma unroll
    for (int r = 0; r < 4; ++r)
      g[(size_t)(m0 + lk * 4 + r) * NC + n] = acc[r] + bb;
  }
}

// --------------------------------------------------------------- fallbacks --
__global__ void __launch_bounds__(256)
k_attn_direct(const float* __restrict__ orig, const unsigned short* __restrict__ h1b,
              float* __restrict__ d_out, int t){
  int b = blockIdx.x, tid = threadIdx.x;
  __shared__ float h1s[HID];
  __shared__ float as[L_];
  h1s[tid]       = bf2f(h1b[(size_t)b * HID + tid]);
  h1s[256 + tid] = bf2f(h1b[(size_t)b * HID + 256 + tid]);
  __syncthreads();
  const float* fb = orig + (size_t)b * HID * L_;
  float dot = 0.f;
  for (int ch = 0; ch < HID; ++ch) dot += h1s[ch] * fb[(size_t)ch * L_ + tid];
  float a = sigm(dot);
  as[tid] = a;
  d_out[MASK_OFF + ((size_t)b * T_ + t) * L_ + tid] = a;
  __syncthreads();
  for (int cc = 0; cc < 2; ++cc){
    int ch = tid + cc * 256;
    float s = 0.f;
    for (int ll = 0; ll < L_; ++ll) s += as[ll] * fb[(size_t)ch * L_ + ll];
    d_out[OH_OFF + ((size_t)b * T_ + t) * HID + ch] = s;
  }
}

__global__ void k_gen_v(const float* __restrict__ ctx, const float* __restrict__ genW,
                        const float* __restrict__ genb, float* __restrict__ g){
  int o = blockIdx.x * 256 + threadIdx.x;
  if (o >= B_ * T_ * NC) return;
  int m = o / NC, n = o - m * NC;
  const float4* a = (const float4*)(ctx + (size_t)m * HID);
  const float4* wv = (const float4*)(genW + (size_t)n * HID);
  float s = genb[n];
  for (int k = 0; k < HID / 4; ++k){
    float4 av = a[k], w = wv[k];
    s += av.x * w.x + av.y * w.y + av.z * w.z + av.w * w.w;
  }
  g[o] = s;
}

// -----------------------------------------------------------------------------
extern "C" void kernel_launch(void* const* d_in, const int* in_sizes, int n_in,
                              void* d_out, int out_size, void* d_ws, size_t ws_size,
                              hipStream_t stream){
  const float* orig = (const float*)d_in[0];
  const int*   text = (const int*)  d_in[1];
  const float* embW = (const float*)d_in[2];
  const float* embb = (const float*)d_in[3];
  const float* Wih0 = (const float*)d_in[4];
  const float* Whh0 = (const float*)d_in[5];
  const float* bih0 = (const float*)d_in[6];
  const float* bhh0 = (const float*)d_in[7];
  const float* Wih1 = (const float*)d_in[8];
  const float* Whh1 = (const float*)d_in[9];
  const float* bih1 = (const float*)d_in[10];
  const float* bhh1 = (const float*)d_in[11];
  const float* genW = (const float*)d_in[12];
  const float* genb = (const float*)d_in[13];
  float* out = (float*)d_out;

  char* p = (char*)d_ws;
  float* embg  = (float*)p;           p += (size_t)NC * G4 * 4;
  float* b1sum = (float*)p;           p += (size_t)G4 * 4;
  float* c0    = (float*)p;           p += (size_t)B_ * HID * 4;   // fallback only
  float* c1    = (float*)p;           p += (size_t)B_ * HID * 4;   // fallback only
  unsigned short* h0p0 = (unsigned short*)p;   p += (size_t)B_ * HID * 2;
  unsigned short* h0p1 = (unsigned short*)p;   p += (size_t)B_ * HID * 2;
  unsigned short* h1p0 = (unsigned short*)p;   p += (size_t)B_ * HID * 2;
  unsigned short* h1p1 = (unsigned short*)p;   p += (size_t)B_ * HID * 2;
  unsigned int* bar = (unsigned int*)p;        p += 256;
  unsigned short* Whh0bf  = (unsigned short*)p; p += (size_t)G4 * 512 * 2;
  unsigned short* Wcat1bf = (unsigned short*)p; p += (size_t)G4 * 1024 * 2;
  unsigned short* Wih0bf  = (unsigned short*)p; p += (size_t)G4 * 512 * 2;
  unsigned short* embXbf  = (unsigned short*)p; p += (size_t)NC * HID * 2;
  unsigned short* genWbf  = (unsigned short*)p; p += (size_t)NC * HID * 2;
  unsigned short* h1all = (unsigned short*)p;  p += (size_t)B_ * T_ * HID * 2;  // 8MB
  unsigned short* Abf   = (unsigned short*)p;  p += (size_t)B_ * T_ * L_ * 2;   // 4MB
  unsigned short* ctxbf = (unsigned short*)p;  p += (size_t)B_ * T_ * HID * 2;  // 8MB
  unsigned short* fmapT = (unsigned short*)p;  p += (size_t)B_ * L_ * HID * 2;  // 64MB
  bool big = ws_size >= (size_t)(p - (char*)d_ws);

  // zero c0,c1, h ping-pong buffers, and the barrier counter (contiguous)
  hipMemsetAsync(c0, 0,
                 (size_t)B_ * HID * 4 * 2 + (size_t)B_ * HID * 2 * 4 + 256, stream);

  k_wconv<<<(G4 * HID + 255) / 256, 256, 0, stream>>>(Whh0, Wih1, Whh1, Wih0,
                                                      Whh0bf, Wcat1bf, Wih0bf);
  k_small<<<(NC * HID + 255) / 256, 256, 0, stream>>>(embW, embb, genW, bih1, bhh1,
                                                      embXbf, genWbf, b1sum);
  k_embg_m<<<dim3(7, G4 / 16), 64, 0, stream>>>(embXbf, Wih0bf, bih0, bhh0, embg);
  if (big) k_fmapT<<<dim3(L_ / 32, HID / 32, B_), dim3(32, 8), 0, stream>>>(orig, fmapT);

  unsigned short* h1all_arg = big ? h1all : h1p0;
  hipError_t ce = hipErrorUnknown;
  {
    const unsigned short* a0 = Whh0bf; const unsigned short* a1 = Wcat1bf;
    const float* a2 = embg; const int* a3 = text; const float* a4 = b1sum;
    unsigned short* a5 = h0p0; unsigned short* a6 = h0p1;
    unsigned short* a7 = h1p0; unsigned short* a8 = h1p1;
    unsigned short* a9 = h1all_arg; unsigned int* a10 = bar;
    void* args[] = {&a0, &a1, &a2, &a3, &a4, &a5, &a6, &a7, &a8, &a9, &a10};
    ce = hipLaunchCooperativeKernel((const void*)k_loop, dim3(256), dim3(256),
                                    args, 0, stream);
  }
  if (ce != hipSuccess){
    // fallback: per-step kernels (ping-pong buffers reused)
    unsigned short* h0bf[2] = {h0p0, h0p1};
    unsigned short* h1bf[2] = {h1p0, h1p1};
    for (int t = 0; t < T_; ++t){
      int ping = t & 1;
      k_lstm2<0><<<dim3(8, 32), 64, 0, stream>>>(h0bf[ping], nullptr, Whh0bf,
          embg, text, nullptr, c0, h0bf[ping ^ 1], nullptr, t);
      k_lstm2<1><<<dim3(8, 32), 64, 0, stream>>>(h0bf[ping ^ 1], h1bf[ping], Wcat1bf,
          nullptr, nullptr, b1sum, c1, h1bf[ping ^ 1], big ? h1all : nullptr, t);
      if (!big) k_attn_direct<<<B_, 256, 0, stream>>>(orig, h1bf[ping ^ 1], out, t);
    }
  }

  if (big){
    k_attn1<<<B_, 256, 0, stream>>>(fmapT, h1all, Abf, out);
    k_attn2<<<B_, 512, 0, stream>>>(fmapT, Abf, out, ctxbf);
    k_gen_m<<<dim3(B_ * T_ / 64, 7), 256, 0, stream>>>(ctxbf, genWbf, genb, out);
  } else {
    k_gen_v<<<(B_ * T_ * NC + 255) / 256, 256, 0, stream>>>(out + OH_OFF, genW, genb, out);
  }
}

// Round 5
// 879.377 us; speedup vs baseline: 3.5407x; 1.1655x over previous
//
#include <hip/hip_runtime.h>

#define B_   256
#define HID  512
#define T_   32
#define L_   256
#define NC   97
#define G4   2048

// d_out layout (f32): g [256,32,97] | output_hiddens [256,32,512] | masks [256,32,8,32]
#define OH_OFF   794624
#define MASK_OFF 4988928

typedef __bf16 v8bf __attribute__((ext_vector_type(8)));
typedef float  v4f  __attribute__((ext_vector_type(4)));

__device__ __forceinline__ unsigned short f2bf(float x){
  unsigned u = __float_as_uint(x);
  u += 0x7FFFu + ((u >> 16) & 1u);          // round-to-nearest-even
  return (unsigned short)(u >> 16);
}
__device__ __forceinline__ float bf2f(unsigned short h){
  return __uint_as_float(((unsigned)h) << 16);
}
__device__ __forceinline__ float sigm(float x){ return 1.f / (1.f + __expf(-x)); }
__device__ __forceinline__ float tanh_f(float x){
  float e = __expf(2.f * x);
  return 1.f - 2.f / (e + 1.f);             // safe at +/-inf
}
__device__ __forceinline__ v8bf ld8(const unsigned short* p){
  return *reinterpret_cast<const v8bf*>(p);
}

// ---------------------------------------------------------------- one-time --
__global__ void k_wconv(const float* __restrict__ Whh0, const float* __restrict__ Wih1,
                        const float* __restrict__ Whh1, const float* __restrict__ Wih0,
                        unsigned short* __restrict__ Whh0bf, unsigned short* __restrict__ Wcat1bf,
                        unsigned short* __restrict__ Wih0bf){
  int i = blockIdx.x * 256 + threadIdx.x;
  if (i >= G4 * HID) return;
  Whh0bf[i] = f2bf(Whh0[i]);
  Wih0bf[i] = f2bf(Wih0[i]);
  int n = i >> 9, k = i & 511;
  Wcat1bf[(size_t)n * 1024 + k]       = f2bf(Wih1[i]);
  Wcat1bf[(size_t)n * 1024 + 512 + k] = f2bf(Whh1[i]);
}

__global__ void k_small(const float* __restrict__ embW, const float* __restrict__ embb,
                        const float* __restrict__ genW, const float* __restrict__ bih1,
                        const float* __restrict__ bhh1,
                        unsigned short* __restrict__ embXbf, unsigned short* __restrict__ genWbf,
                        float* __restrict__ b1sum){
  int i = blockIdx.x * 256 + threadIdx.x;
  if (i < NC * HID){
    int c = i >> 9, h = i & 511;
    embXbf[i] = f2bf(embW[h * NC + c] + embb[h]);
    genWbf[i] = f2bf(genW[i]);
  }
  if (i < G4) b1sum[i] = bih1[i] + bhh1[i];
}

// emb_gates[c][n] (MFMA, M=97 N=2048 K=512)
__global__ void __launch_bounds__(64)
k_embg_m(const unsigned short* __restrict__ embXbf, const unsigned short* __restrict__ Wih0bf,
         const float* __restrict__ bih0, const float* __restrict__ bhh0,
         float* __restrict__ embg){
  int m0 = blockIdx.x * 16, j0 = blockIdx.y * 16;
  int l = threadIdx.x, lr = l & 15, lk = l >> 4;
  int ar = min(m0 + lr, NC - 1);
  v4f acc = {0,0,0,0};
  for (int ks = 0; ks < 16; ++ks){
    int kb = ks * 32 + lk * 8;
    v8bf a  = ld8(embXbf + (size_t)ar * HID + kb);
    v8bf bf = ld8(Wih0bf + (size_t)(j0 + lr) * HID + kb);
    acc = __builtin_amdgcn_mfma_f32_16x16x32_bf16(a, bf, acc, 0, 0, 0);
  }
  int n = j0 + lr;
  float bb = bih0[n] + bhh0[n];
#pragma unroll
  for (int r = 0; r < 4; ++r){
    int c = m0 + lk * 4 + r;
    if (c < NC) embg[(size_t)c * G4 + n] = acc[r] + bb;
  }
}

// origin[b][c][l] f32 -> fmapT[b][l][c] bf16
__global__ void k_fmapT(const float* __restrict__ orig, unsigned short* __restrict__ fT){
  __shared__ float tile[32][33];
  int b = blockIdx.z, c0 = blockIdx.y * 32, l0 = blockIdx.x * 32;
  const float* src = orig + ((size_t)b * HID + c0) * L_ + l0;
  for (int i = 0; i < 32; i += 8)
    tile[threadIdx.y + i][threadIdx.x] = src[(threadIdx.y + i) * L_ + threadIdx.x];
  __syncthreads();
  unsigned short* dst = fT + ((size_t)b * L_ + l0) * HID + c0;
  for (int i = 0; i < 32; i += 8)
    dst[(threadIdx.y + i) * HID + threadIdx.x] = f2bf(tile[threadIdx.x][threadIdx.y + i]);
}

// -------------------------------------------- persistent pipelined LSTM -----
// 256 blocks x 256 thr (cooperative, 1 block/CU). Blocks 0..127 = LSTM0,
// 128..255 = LSTM1 (pipelined: phase p runs LSTM0 step p and LSTM1 step p-1).
// Cross-block h-state passes through coherent (agent-scope, L2-bypassing)
// atomics only; weights stay L2-resident (no fences, no cache flush).
// Grid barrier = contention-free flags: per-block arrival flag (own cacheline),
// block 0 aggregates, release via 8 replicated lines (<=32 pollers each).
__global__ void __launch_bounds__(256, 1)
k_loop(const unsigned short* __restrict__ Whh0bf,
       const unsigned short* __restrict__ Wcat1bf,
       const float* __restrict__ embg, const int* __restrict__ text,
       const float* __restrict__ b1sum,
       unsigned short* h0p0, unsigned short* h0p1,
       unsigned short* h1p0, unsigned short* h1p1,
       unsigned short* h1all, unsigned int* flags, unsigned int* rel){
  const int bid = blockIdx.x;
  const bool isB = bid >= 128;
  const int gb = isB ? bid - 128 : bid;
  const int tid = threadIdx.x;
  const int w = tid >> 6, l = tid & 63, lr = l & 15, lk = l >> 4;
  const int gw = gb * 4 + w;                 // 0..511
  const int m0 = ((gb * 4) >> 5) * 16;       // block-uniform m-tile (16 rows)
  const int j0 = (gw & 31) * 16;
  const int j  = j0 + lr;

  __shared__ unsigned short hS[16][1048];    // A: cols 0..511; B: h0|h1 0..1023

  float creg0 = 0.f, creg1 = 0.f, creg2 = 0.f, creg3 = 0.f;
  float xb0 = 0.f, xb1 = 0.f, xb2 = 0.f, xb3 = 0.f;
  if (isB){
    xb0 = b1sum[j]; xb1 = b1sum[512 + j];
    xb2 = b1sum[1024 + j]; xb3 = b1sum[1536 + j];
  }
  const unsigned short* W = isB ? Wcat1bf : Whh0bf;
  const int wstr = isB ? 1024 : 512;
  const int KS   = isB ? 32 : 16;
  const int nld  = isB ? 16 : 8;             // u64 stage-loads per thread

  for (int p = 0; p <= 32; ++p){
    const bool active = isB ? (p >= 1) : (p < 32);
    if (active){
      const int t = isB ? (p - 1) : p;
      const unsigned short* hA = ((p + 1) & 1) ? h0p1 : h0p0;  // h0(p-1)
      const unsigned short* hB = (p & 1) ? h1p1 : h1p0;        // h1(p-2), B only

      // ---- stage h rows m0..m0+15 into LDS via coherent (L2-bypass) loads
      for (int i = 0; i < nld; ++i){
        int e = tid + 256 * i;
        int part = e >> 11;                  // 0: hA, 1: hB (B only)
        int ei = e & 2047;
        int row = ei >> 7, c4 = (ei & 127) * 4;
        const unsigned short* src = part ? hB : hA;
        unsigned long long v = __hip_atomic_load(
            (const unsigned long long*)(src + (size_t)(m0 + row) * HID + c4),
            __ATOMIC_RELAXED, __HIP_MEMORY_SCOPE_AGENT);
        *(unsigned long long*)&hS[row][part * 512 + c4] = v;
      }
      __syncthreads();

      // ---- MFMA: 16 rows x 16 j x 4 gates, full K
      v4f acc0 = {0,0,0,0}, acc1 = {0,0,0,0}, acc2 = {0,0,0,0}, acc3 = {0,0,0,0};
#pragma unroll 4
      for (int ks = 0; ks < KS; ++ks){
        const int kb = ks * 32 + lk * 8;
        v8bf a  = *(const v8bf*)&hS[lr][kb];
        v8bf b0 = ld8(W + (size_t)(0 * HID + j0 + lr) * wstr + kb);
        v8bf b1 = ld8(W + (size_t)(1 * HID + j0 + lr) * wstr + kb);
        v8bf b2 = ld8(W + (size_t)(2 * HID + j0 + lr) * wstr + kb);
        v8bf b3 = ld8(W + (size_t)(3 * HID + j0 + lr) * wstr + kb);
        acc0 = __builtin_amdgcn_mfma_f32_16x16x32_bf16(a, b0, acc0, 0, 0, 0);
        acc1 = __builtin_amdgcn_mfma_f32_16x16x32_bf16(a, b1, acc1, 0, 0, 0);
        acc2 = __builtin_amdgcn_mfma_f32_16x16x32_bf16(a, b2, acc2, 0, 0, 0);
        acc3 = __builtin_amdgcn_mfma_f32_16x16x32_bf16(a, b3, acc3, 0, 0, 0);
      }

      unsigned short* hout = isB ? ((p & 1) ? h1p0 : h1p1)   // h1(p-1)
                                 : ((p & 1) ? h0p1 : h0p0);  // h0(p)
#pragma unroll
      for (int r = 0; r < 4; ++r){
        const int brow = m0 + lk * 4 + r;
        float xi, xf, xg, xo;
        if (!isB){
          const float* eg = embg + (size_t)text[brow * T_ + t] * G4 + j;
          xi = eg[0]; xf = eg[512]; xg = eg[1024]; xo = eg[1536];
        } else {
          xi = xb0; xf = xb1; xg = xb2; xo = xb3;
        }
        float ig = acc0[r] + xi, fg = acc1[r] + xf;
        float gg = acc2[r] + xg, og = acc3[r] + xo;
        float cprev = (r == 0) ? creg0 : (r == 1) ? creg1 : (r == 2) ? creg2 : creg3;
        float cn = sigm(fg) * cprev + sigm(ig) * tanh_f(gg);
        if (r == 0) creg0 = cn; else if (r == 1) creg1 = cn;
        else if (r == 2) creg2 = cn; else creg3 = cn;
        float hn = sigm(og) * tanh_f(cn);
        unsigned v = f2bf(hn);
        unsigned pv = (unsigned)__shfl_xor((int)v, 1);       // partner col
        if (!(lr & 1)){
          unsigned pack = (v & 0xFFFFu) | (pv << 16);        // cols (j, j+1)
          __hip_atomic_store((unsigned*)(hout + (size_t)brow * HID + j), pack,
                             __ATOMIC_RELAXED, __HIP_MEMORY_SCOPE_AGENT);
        }
        if (isB) h1all[((size_t)brow * T_ + t) * HID + j] = (unsigned short)v;
      }
    }
    // ---- flag barrier: arrive (own line) -> block0 aggregates -> 8-line release
    if (p != 32){
      const unsigned tgt = (unsigned)(p + 1);
      __syncthreads();                        // drains vmcnt: h-stores ack'd
      if (tid == 0)
        __hip_atomic_store(&flags[bid * 16], tgt,
                           __ATOMIC_RELAXED, __HIP_MEMORY_SCOPE_AGENT);
      if (bid == 0){
        while (__hip_atomic_load(&flags[tid * 16],
                                 __ATOMIC_RELAXED, __HIP_MEMORY_SCOPE_AGENT) < tgt)
          __builtin_amdgcn_s_sleep(2);
        __syncthreads();
        if (tid < 8)
          __hip_atomic_store(&rel[tid * 16], tgt,
                             __ATOMIC_RELAXED, __HIP_MEMORY_SCOPE_AGENT);
      } else {
        if (tid == 0){
          while (__hip_atomic_load(&rel[(bid & 7) * 16],
                                   __ATOMIC_RELAXED, __HIP_MEMORY_SCOPE_AGENT) < tgt)
            __builtin_amdgcn_s_sleep(2);
        }
        __syncthreads();
      }
    }
  }
}

// ---------------------------------------------------- per-step LSTM (fallback)
template<int MODE>
__global__ void __launch_bounds__(64)
k_lstm2(const unsigned short* __restrict__ hA1, const unsigned short* __restrict__ hA2,
        const unsigned short* __restrict__ Wbf,
        const float* __restrict__ embg, const int* __restrict__ text,
        const float* __restrict__ b1sum,
        float* __restrict__ cstate, unsigned short* __restrict__ hout,
        unsigned short* __restrict__ h1all, int t){
  const int KS = MODE ? 32 : 16;
  const int wstr = MODE ? 1024 : 512;
  int m0 = blockIdx.x * 32, j0 = blockIdx.y * 16;
  int l = threadIdx.x, lr = l & 15, lk = l >> 4;
  v4f acc[2][4] = {};
  for (int ks = 0; ks < KS; ++ks){
    int kb = ks * 32 + lk * 8;
    const unsigned short* Ap = (MODE == 1 && ks >= 16) ? hA2 : hA1;
    int ka = (MODE == 1 && ks >= 16) ? (kb - 512) : kb;
    v8bf a0 = ld8(Ap + (size_t)(m0 + lr) * HID + ka);
    v8bf a1 = ld8(Ap + (size_t)(m0 + 16 + lr) * HID + ka);
#pragma unroll
    for (int g = 0; g < 4; ++g){
      v8bf bf = ld8(Wbf + (size_t)(g * HID + j0 + lr) * wstr + kb);
      acc[0][g] = __builtin_amdgcn_mfma_f32_16x16x32_bf16(a0, bf, acc[0][g], 0, 0, 0);
      acc[1][g] = __builtin_amdgcn_mfma_f32_16x16x32_bf16(a1, bf, acc[1][g], 0, 0, 0);
    }
  }
  int j = j0 + lr;
  float xi = 0.f, xf = 0.f, xg = 0.f, xo = 0.f;
  if (MODE == 1){
    xi = b1sum[j]; xf = b1sum[512 + j]; xg = b1sum[1024 + j]; xo = b1sum[1536 + j];
  }
#pragma unroll
  for (int fm = 0; fm < 2; ++fm){
#pragma unroll
    for (int r = 0; r < 4; ++r){
      int b = m0 + fm * 16 + lk * 4 + r;
      if (MODE == 0){
        const float* eg = embg + (size_t)text[b * T_ + t] * G4 + j;
        xi = eg[0]; xf = eg[512]; xg = eg[1024]; xo = eg[1536];
      }
      float ig = acc[fm][0][r] + xi, fg = acc[fm][1][r] + xf;
      float gg = acc[fm][2][r] + xg, og = acc[fm][3][r] + xo;
      size_t s = (size_t)b * HID + j;
      float cn = sigm(fg) * cstate[s] + sigm(ig) * tanh_f(gg);
      cstate[s] = cn;
      float hn = sigm(og) * tanh_f(cn);
      hout[s] = f2bf(hn);
      if (MODE == 1 && h1all != nullptr)
        h1all[((size_t)b * T_ + t) * HID + j] = f2bf(hn);
    }
  }
}

// ----------------------------------------------------- batched attention ----
__global__ void __launch_bounds__(256)
k_attn1(const unsigned short* __restrict__ fT, const unsigned short* __restrict__ h1all,
        unsigned short* __restrict__ Abf, float* __restrict__ d_out){
  int b = blockIdx.x, tid = threadIdx.x, w = tid >> 6, l = tid & 63;
  int lr = l & 15, lk = l >> 4;
  const unsigned short* hb = h1all + (size_t)b * T_ * HID;
  const unsigned short* fb = fT + (size_t)b * L_ * HID;
  v4f acc[2][4] = {};
  for (int ks = 0; ks < 16; ++ks){
    int kb = ks * 32 + lk * 8;
    v8bf a0 = ld8(hb + (size_t)lr * HID + kb);
    v8bf a1 = ld8(hb + (size_t)(16 + lr) * HID + kb);
#pragma unroll
    for (int fn = 0; fn < 4; ++fn){
      v8bf bf = ld8(fb + (size_t)(w * 64 + fn * 16 + lr) * HID + kb);
      acc[0][fn] = __builtin_amdgcn_mfma_f32_16x16x32_bf16(a0, bf, acc[0][fn], 0, 0, 0);
      acc[1][fn] = __builtin_amdgcn_mfma_f32_16x16x32_bf16(a1, bf, acc[1][fn], 0, 0, 0);
    }
  }
#pragma unroll
  for (int fm = 0; fm < 2; ++fm)
#pragma unroll
    for (int fn = 0; fn < 4; ++fn)
#pragma unroll
      for (int r = 0; r < 4; ++r){
        int tt = fm * 16 + lk * 4 + r;
        int li = w * 64 + fn * 16 + lr;
        float aa = sigm(acc[fm][fn][r]);
        d_out[MASK_OFF + ((size_t)b * T_ + tt) * L_ + li] = aa;
        Abf[((size_t)b * T_ + tt) * L_ + li] = f2bf(aa);
      }
}

__global__ void __launch_bounds__(512)
k_attn2(const unsigned short* __restrict__ fT, const unsigned short* __restrict__ Abf,
        float* __restrict__ d_out, unsigned short* __restrict__ ctxbf){
  int b = blockIdx.x, tid = threadIdx.x, w = tid >> 6, l = tid & 63;
  __shared__ float aS[T_][L_];
  const unsigned short* ab = Abf + (size_t)b * T_ * L_;
  for (int i = tid * 8; i < T_ * L_; i += 512 * 8){
    ushort4 u0 = *(const ushort4*)(ab + i);
    ushort4 u1 = *(const ushort4*)(ab + i + 4);
    int tt = i >> 8, ll = i & 255;
    aS[tt][ll+0] = bf2f(u0.x); aS[tt][ll+1] = bf2f(u0.y);
    aS[tt][ll+2] = bf2f(u0.z); aS[tt][ll+3] = bf2f(u0.w);
    aS[tt][ll+4] = bf2f(u1.x); aS[tt][ll+5] = bf2f(u1.y);
    aS[tt][ll+6] = bf2f(u1.z); aS[tt][ll+7] = bf2f(u1.w);
  }
  __syncthreads();
  float acc[4][8] = {};
  const unsigned short* fb = fT + (size_t)b * L_ * HID + l * 8;
  for (int li = 0; li < L_; ++li){
    ushort4 u0 = *(const ushort4*)(fb + (size_t)li * HID);
    ushort4 u1 = *(const ushort4*)(fb + (size_t)li * HID + 4);
    float f[8] = {bf2f(u0.x), bf2f(u0.y), bf2f(u0.z), bf2f(u0.w),
                  bf2f(u1.x), bf2f(u1.y), bf2f(u1.z), bf2f(u1.w)};
#pragma unroll
    for (int tt = 0; tt < 4; ++tt){
      float a = aS[w * 4 + tt][li];
#pragma unroll
      for (int k = 0; k < 8; ++k) acc[tt][k] += a * f[k];
    }
  }
#pragma unroll
  for (int tt = 0; tt < 4; ++tt)
#pragma unroll
    for (int k = 0; k < 8; ++k){
      size_t o = ((size_t)b * T_ + w * 4 + tt) * HID + l * 8 + k;
      d_out[OH_OFF + o] = acc[tt][k];
      ctxbf[o] = f2bf(acc[tt][k]);
    }
}

// ------------------------------------------------------------------ final ---
__global__ void __launch_bounds__(256)
k_gen_m(const unsigned short* __restrict__ ctxbf, const unsigned short* __restrict__ genWbf,
        const float* __restrict__ genb, float* __restrict__ g){
  int m0 = blockIdx.x * 64 + (threadIdx.x >> 6) * 16;
  int j0 = blockIdx.y * 16;
  int l = threadIdx.x & 63, lr = l & 15, lk = l >> 4;
  int n = j0 + lr, nr = min(n, NC - 1);
  v4f acc = {0,0,0,0};
  for (int ks = 0; ks < 16; ++ks){
    int kb = ks * 32 + lk * 8;
    v8bf a  = ld8(ctxbf + (size_t)(m0 + lr) * HID + kb);
    v8bf bf = ld8(genWbf + (size_t)nr * HID + kb);
    acc = __builtin_amdgcn_mfma_f32_16x16x32_bf16(a, bf, acc, 0, 0, 0);
  }
  if (n < NC){
    float bb = genb[n];
#pragma unroll
    for (int r = 0; r < 4; ++r)
      g[(size_t)(m0 + lk * 4 + r) * NC + n] = acc[r] + bb;
  }
}

// --------------------------------------------------------------- fallbacks --
__global__ void __launch_bounds__(256)
k_attn_direct(const float* __restrict__ orig, const unsigned short* __restrict__ h1b,
              float* __restrict__ d_out, int t){
  int b = blockIdx.x, tid = threadIdx.x;
  __shared__ float h1s[HID];
  __shared__ float as[L_];
  h1s[tid]       = bf2f(h1b[(size_t)b * HID + tid]);
  h1s[256 + tid] = bf2f(h1b[(size_t)b * HID + 256 + tid]);
  __syncthreads();
  const float* fb = orig + (size_t)b * HID * L_;
  float dot = 0.f;
  for (int ch = 0; ch < HID; ++ch) dot += h1s[ch] * fb[(size_t)ch * L_ + tid];
  float a = sigm(dot);
  as[tid] = a;
  d_out[MASK_OFF + ((size_t)b * T_ + t) * L_ + tid] = a;
  __syncthreads();
  for (int cc = 0; cc < 2; ++cc){
    int ch = tid + cc * 256;
    float s = 0.f;
    for (int ll = 0; ll < L_; ++ll) s += as[ll] * fb[(size_t)ch * L_ + ll];
    d_out[OH_OFF + ((size_t)b * T_ + t) * HID + ch] = s;
  }
}

__global__ void k_gen_v(const float* __restrict__ ctx, const float* __restrict__ genW,
                        const float* __restrict__ genb, float* __restrict__ g){
  int o = blockIdx.x * 256 + threadIdx.x;
  if (o >= B_ * T_ * NC) return;
  int m = o / NC, n = o - m * NC;
  const float4* a = (const float4*)(ctx + (size_t)m * HID);
  const float4* wv = (const float4*)(genW + (size_t)n * HID);
  float s = genb[n];
  for (int k = 0; k < HID / 4; ++k){
    float4 av = a[k], w = wv[k];
    s += av.x * w.x + av.y * w.y + av.z * w.z + av.w * w.w;
  }
  g[o] = s;
}

// -----------------------------------------------------------------------------
extern "C" void kernel_launch(void* const* d_in, const int* in_sizes, int n_in,
                              void* d_out, int out_size, void* d_ws, size_t ws_size,
                              hipStream_t stream){
  const float* orig = (const float*)d_in[0];
  const int*   text = (const int*)  d_in[1];
  const float* embW = (const float*)d_in[2];
  const float* embb = (const float*)d_in[3];
  const float* Wih0 = (const float*)d_in[4];
  const float* Whh0 = (const float*)d_in[5];
  const float* bih0 = (const float*)d_in[6];
  const float* bhh0 = (const float*)d_in[7];
  const float* Wih1 = (const float*)d_in[8];
  const float* Whh1 = (const float*)d_in[9];
  const float* bih1 = (const float*)d_in[10];
  const float* bhh1 = (const float*)d_in[11];
  const float* genW = (const float*)d_in[12];
  const float* genb = (const float*)d_in[13];
  float* out = (float*)d_out;

  char* p = (char*)d_ws;
  float* embg  = (float*)p;           p += (size_t)NC * G4 * 4;
  float* b1sum = (float*)p;           p += (size_t)G4 * 4;
  // ---- zero-init region start (c0 .. rel, contiguous) ----
  float* c0    = (float*)p;           p += (size_t)B_ * HID * 4;   // fallback only
  float* c1    = (float*)p;           p += (size_t)B_ * HID * 4;   // fallback only
  unsigned short* h0p0 = (unsigned short*)p;   p += (size_t)B_ * HID * 2;
  unsigned short* h0p1 = (unsigned short*)p;   p += (size_t)B_ * HID * 2;
  unsigned short* h1p0 = (unsigned short*)p;   p += (size_t)B_ * HID * 2;
  unsigned short* h1p1 = (unsigned short*)p;   p += (size_t)B_ * HID * 2;
  unsigned int* flags = (unsigned int*)p;      p += 256 * 64;       // 1 line/block
  unsigned int* rel   = (unsigned int*)p;      p += 8 * 64;         // 8 release lines
  size_t zbytes = (size_t)((char*)p - (char*)c0);
  // ---- zero-init region end ----
  unsigned short* Whh0bf  = (unsigned short*)p; p += (size_t)G4 * 512 * 2;
  unsigned short* Wcat1bf = (unsigned short*)p; p += (size_t)G4 * 1024 * 2;
  unsigned short* Wih0bf  = (unsigned short*)p; p += (size_t)G4 * 512 * 2;
  unsigned short* embXbf  = (unsigned short*)p; p += (size_t)NC * HID * 2;
  unsigned short* genWbf  = (unsigned short*)p; p += (size_t)NC * HID * 2;
  unsigned short* h1all = (unsigned short*)p;  p += (size_t)B_ * T_ * HID * 2;  // 8MB
  unsigned short* Abf   = (unsigned short*)p;  p += (size_t)B_ * T_ * L_ * 2;   // 4MB
  unsigned short* ctxbf = (unsigned short*)p;  p += (size_t)B_ * T_ * HID * 2;  // 8MB
  unsigned short* fmapT = (unsigned short*)p;  p += (size_t)B_ * L_ * HID * 2;  // 64MB
  bool big = ws_size >= (size_t)(p - (char*)d_ws);

  hipMemsetAsync(c0, 0, zbytes, stream);

  k_wconv<<<(G4 * HID + 255) / 256, 256, 0, stream>>>(Whh0, Wih1, Whh1, Wih0,
                                                      Whh0bf, Wcat1bf, Wih0bf);
  k_small<<<(NC * HID + 255) / 256, 256, 0, stream>>>(embW, embb, genW, bih1, bhh1,
                                                      embXbf, genWbf, b1sum);
  k_embg_m<<<dim3(7, G4 / 16), 64, 0, stream>>>(embXbf, Wih0bf, bih0, bhh0, embg);
  if (big) k_fmapT<<<dim3(L_ / 32, HID / 32, B_), dim3(32, 8), 0, stream>>>(orig, fmapT);

  unsigned short* h1all_arg = big ? h1all : h1p0;
  hipError_t ce = hipErrorUnknown;
  {
    const unsigned short* a0 = Whh0bf; const unsigned short* a1 = Wcat1bf;
    const float* a2 = embg; const int* a3 = text; const float* a4 = b1sum;
    unsigned short* a5 = h0p0; unsigned short* a6 = h0p1;
    unsigned short* a7 = h1p0; unsigned short* a8 = h1p1;
    unsigned short* a9 = h1all_arg; unsigned int* a10 = flags; unsigned int* a11 = rel;
    void* args[] = {&a0, &a1, &a2, &a3, &a4, &a5, &a6, &a7, &a8, &a9, &a10, &a11};
    ce = hipLaunchCooperativeKernel((const void*)k_loop, dim3(256), dim3(256),
                                    args, 0, stream);
  }
  if (ce != hipSuccess){
    // fallback: per-step kernels (ping-pong buffers reused)
    unsigned short* h0bf[2] = {h0p0, h0p1};
    unsigned short* h1bf[2] = {h1p0, h1p1};
    for (int t = 0; t < T_; ++t){
      int ping = t & 1;
      k_lstm2<0><<<dim3(8, 32), 64, 0, stream>>>(h0bf[ping], nullptr, Whh0bf,
          embg, text, nullptr, c0, h0bf[ping ^ 1], nullptr, t);
      k_lstm2<1><<<dim3(8, 32), 64, 0, stream>>>(h0bf[ping ^ 1], h1bf[ping], Wcat1bf,
          nullptr, nullptr, b1sum, c1, h1bf[ping ^ 1], big ? h1all : nullptr, t);
      if (!big) k_attn_direct<<<B_, 256, 0, stream>>>(orig, h1bf[ping ^ 1], out, t);
    }
  }

  if (big){
    k_attn1<<<B_, 256, 0, stream>>>(fmapT, h1all, Abf, out);
    k_attn2<<<B_, 512, 0, stream>>>(fmapT, Abf, out, ctxbf);
    k_gen_m<<<dim3(B_ * T_ / 64, 7), 256, 0, stream>>>(ctxbf, genWbf, genb, out);
  } else {
    k_gen_v<<<(B_ * T_ * NC + 255) / 256, 256, 0, stream>>>(out + OH_OFF, genW, genb, out);
  }
}

// Round 6
// 811.709 us; speedup vs baseline: 3.8358x; 1.0834x over previous
//
#include <hip/hip_runtime.h>

#define B_   256
#define HID  512
#define T_   32
#define L_   256
#define NC   97
#define G4   2048

// d_out layout (f32): g [256,32,97] | output_hiddens [256,32,512] | masks [256,32,8,32]
#define OH_OFF   794624
#define MASK_OFF 4988928

typedef __bf16 v8bf __attribute__((ext_vector_type(8)));
typedef float  v4f  __attribute__((ext_vector_type(4)));
typedef unsigned int v4u __attribute__((ext_vector_type(4)));

__device__ __forceinline__ unsigned short f2bf(float x){
  unsigned u = __float_as_uint(x);
  u += 0x7FFFu + ((u >> 16) & 1u);          // round-to-nearest-even
  return (unsigned short)(u >> 16);
}
__device__ __forceinline__ float bf2f(unsigned short h){
  return __uint_as_float(((unsigned)h) << 16);
}
__device__ __forceinline__ float sigm(float x){ return 1.f / (1.f + __expf(-x)); }
__device__ __forceinline__ float tanh_f(float x){
  float e = __expf(2.f * x);
  return 1.f - 2.f / (e + 1.f);             // safe at +/-inf
}
__device__ __forceinline__ v8bf ld8(const unsigned short* p){
  return *reinterpret_cast<const v8bf*>(p);
}

// ---------------------------------------------------------------- one-time --
__global__ void k_wconv(const float* __restrict__ Whh0, const float* __restrict__ Wih1,
                        const float* __restrict__ Whh1, const float* __restrict__ Wih0,
                        unsigned short* __restrict__ Whh0bf, unsigned short* __restrict__ Wcat1bf,
                        unsigned short* __restrict__ Wih0bf){
  int i = blockIdx.x * 256 + threadIdx.x;
  if (i >= G4 * HID) return;
  Whh0bf[i] = f2bf(Whh0[i]);
  Wih0bf[i] = f2bf(Wih0[i]);
  int n = i >> 9, k = i & 511;
  Wcat1bf[(size_t)n * 1024 + k]       = f2bf(Wih1[i]);
  Wcat1bf[(size_t)n * 1024 + 512 + k] = f2bf(Whh1[i]);
}

__global__ void k_small(const float* __restrict__ embW, const float* __restrict__ embb,
                        const float* __restrict__ genW, const float* __restrict__ bih1,
                        const float* __restrict__ bhh1,
                        unsigned short* __restrict__ embXbf, unsigned short* __restrict__ genWbf,
                        float* __restrict__ b1sum){
  int i = blockIdx.x * 256 + threadIdx.x;
  if (i < NC * HID){
    int c = i >> 9, h = i & 511;
    embXbf[i] = f2bf(embW[h * NC + c] + embb[h]);
    genWbf[i] = f2bf(genW[i]);
  }
  if (i < G4) b1sum[i] = bih1[i] + bhh1[i];
}

// emb_gates[c][n] (MFMA, M=97 N=2048 K=512)
__global__ void __launch_bounds__(64)
k_embg_m(const unsigned short* __restrict__ embXbf, const unsigned short* __restrict__ Wih0bf,
         const float* __restrict__ bih0, const float* __restrict__ bhh0,
         float* __restrict__ embg){
  int m0 = blockIdx.x * 16, j0 = blockIdx.y * 16;
  int l = threadIdx.x, lr = l & 15, lk = l >> 4;
  int ar = min(m0 + lr, NC - 1);
  v4f acc = {0,0,0,0};
  for (int ks = 0; ks < 16; ++ks){
    int kb = ks * 32 + lk * 8;
    v8bf a  = ld8(embXbf + (size_t)ar * HID + kb);
    v8bf bf = ld8(Wih0bf + (size_t)(j0 + lr) * HID + kb);
    acc = __builtin_amdgcn_mfma_f32_16x16x32_bf16(a, bf, acc, 0, 0, 0);
  }
  int n = j0 + lr;
  float bb = bih0[n] + bhh0[n];
#pragma unroll
  for (int r = 0; r < 4; ++r){
    int c = m0 + lk * 4 + r;
    if (c < NC) embg[(size_t)c * G4 + n] = acc[r] + bb;
  }
}

// origin[b][c][l] f32 -> fmapT[b][l][c] bf16
__global__ void k_fmapT(const float* __restrict__ orig, unsigned short* __restrict__ fT){
  __shared__ float tile[32][33];
  int b = blockIdx.z, c0 = blockIdx.y * 32, l0 = blockIdx.x * 32;
  const float* src = orig + ((size_t)b * HID + c0) * L_ + l0;
  for (int i = 0; i < 32; i += 8)
    tile[threadIdx.y + i][threadIdx.x] = src[(threadIdx.y + i) * L_ + threadIdx.x];
  __syncthreads();
  unsigned short* dst = fT + ((size_t)b * L_ + l0) * HID + c0;
  for (int i = 0; i < 32; i += 8)
    dst[(threadIdx.y + i) * HID + threadIdx.x] = f2bf(tile[threadIdx.x][threadIdx.y + i]);
}

// -------------------------------------------- persistent pipelined LSTM -----
// 256 blocks x 256 thr (cooperative, 1 block/CU). Blocks 0..127 = LSTM0,
// 128..255 = LSTM1 (pipelined: phase p runs LSTM0 step p and LSTM1 step p-1).
// h-state RING (33 slots/chain): stores are agent-scope coherent (write-through
// to MALL); every slot address is VIRGIN, so readers use normal NT dwordx4
// loads -- a never-touched line can't be stale in any L2, and the read runs on
// the full-BW cached path instead of the slow atomic-bypass path.
// Weights stay L2-resident (no fences, no cache flush, nt loads don't pollute).
// Grid barrier = contention-free flags (round-5 design, unchanged).
__global__ void __launch_bounds__(256, 1)
k_loop(const unsigned short* __restrict__ Whh0bf,
       const unsigned short* __restrict__ Wcat1bf,
       const float* __restrict__ embg, const int* __restrict__ text,
       const float* __restrict__ b1sum,
       unsigned short* h0r, unsigned short* h1r,
       unsigned int* flags, unsigned int* rel){
  const int SLOT = B_ * HID;                 // elements per ring slot
  const int bid = blockIdx.x;
  const bool isB = bid >= 128;
  const int gb = isB ? bid - 128 : bid;
  const int tid = threadIdx.x;
  const int w = tid >> 6, l = tid & 63, lr = l & 15, lk = l >> 4;
  const int gw = gb * 4 + w;                 // 0..511
  const int m0 = ((gb * 4) >> 5) * 16;       // block-uniform m-tile (16 rows)
  const int j0 = (gw & 31) * 16;
  const int j  = j0 + lr;

  __shared__ unsigned short hS[16][1048];    // A: cols 0..511; B: h0|h1 0..1023

  float creg0 = 0.f, creg1 = 0.f, creg2 = 0.f, creg3 = 0.f;
  float xb0 = 0.f, xb1 = 0.f, xb2 = 0.f, xb3 = 0.f;
  if (isB){
    xb0 = b1sum[j]; xb1 = b1sum[512 + j];
    xb2 = b1sum[1024 + j]; xb3 = b1sum[1536 + j];
  }
  const unsigned short* W = isB ? Wcat1bf : Whh0bf;
  const int wstr = isB ? 1024 : 512;
  const int KS   = isB ? 32 : 16;
  const int nld  = isB ? 8 : 4;              // nt dwordx4 stage-loads / thread

  for (int p = 0; p <= 32; ++p){
    const bool active = isB ? (p >= 1) : (p < 32);
    if (active){
      const int t = isB ? (p - 1) : p;
      const unsigned short* hA = h0r + (size_t)p * SLOT;        // h0(p)
      const unsigned short* hB = h1r + (size_t)(p - 1) * SLOT;  // h1(p-1), B only

      // ---- stage h band rows m0..m0+15 into LDS (normal NT 16B loads)
      for (int i = 0; i < nld; ++i){
        int e = tid + 256 * i;               // 16B-chunk id
        int part = e >> 10;                  // 0: hA, 1: hB (B only)
        int ei = e & 1023;
        int row = ei >> 6, cc = (ei & 63) * 8;
        const unsigned short* src = part ? hB : hA;
        v4u v = __builtin_nontemporal_load(
            (const v4u*)(src + (size_t)(m0 + row) * HID + cc));
        *(v4u*)&hS[row][part * 512 + cc] = v;
      }
      __syncthreads();

      // ---- MFMA: 16 rows x 16 j x 4 gates, full K
      v4f acc0 = {0,0,0,0}, acc1 = {0,0,0,0}, acc2 = {0,0,0,0}, acc3 = {0,0,0,0};
#pragma unroll 4
      for (int ks = 0; ks < KS; ++ks){
        const int kb = ks * 32 + lk * 8;
        v8bf a  = *(const v8bf*)&hS[lr][kb];
        v8bf b0 = ld8(W + (size_t)(0 * HID + j0 + lr) * wstr + kb);
        v8bf b1 = ld8(W + (size_t)(1 * HID + j0 + lr) * wstr + kb);
        v8bf b2 = ld8(W + (size_t)(2 * HID + j0 + lr) * wstr + kb);
        v8bf b3 = ld8(W + (size_t)(3 * HID + j0 + lr) * wstr + kb);
        acc0 = __builtin_amdgcn_mfma_f32_16x16x32_bf16(a, b0, acc0, 0, 0, 0);
        acc1 = __builtin_amdgcn_mfma_f32_16x16x32_bf16(a, b1, acc1, 0, 0, 0);
        acc2 = __builtin_amdgcn_mfma_f32_16x16x32_bf16(a, b2, acc2, 0, 0, 0);
        acc3 = __builtin_amdgcn_mfma_f32_16x16x32_bf16(a, b3, acc3, 0, 0, 0);
      }

      unsigned short* hout = isB ? (h1r + (size_t)p * SLOT)        // h1(p)
                                 : (h0r + (size_t)(p + 1) * SLOT); // h0(p+1)
#pragma unroll
      for (int r = 0; r < 4; ++r){
        const int brow = m0 + lk * 4 + r;
        float xi, xf, xg, xo;
        if (!isB){
          const float* eg = embg + (size_t)text[brow * T_ + t] * G4 + j;
          xi = eg[0]; xf = eg[512]; xg = eg[1024]; xo = eg[1536];
        } else {
          xi = xb0; xf = xb1; xg = xb2; xo = xb3;
        }
        float ig = acc0[r] + xi, fg = acc1[r] + xf;
        float gg = acc2[r] + xg, og = acc3[r] + xo;
        float cprev = (r == 0) ? creg0 : (r == 1) ? creg1 : (r == 2) ? creg2 : creg3;
        float cn = sigm(fg) * cprev + sigm(ig) * tanh_f(gg);
        if (r == 0) creg0 = cn; else if (r == 1) creg1 = cn;
        else if (r == 2) creg2 = cn; else creg3 = cn;
        float hn = sigm(og) * tanh_f(cn);
        unsigned v = f2bf(hn);
        unsigned pv = (unsigned)__shfl_xor((int)v, 1);       // partner col
        if (!(lr & 1)){
          unsigned pack = (v & 0xFFFFu) | (pv << 16);        // cols (j, j+1)
          __hip_atomic_store((unsigned*)(hout + (size_t)brow * HID + j), pack,
                             __ATOMIC_RELAXED, __HIP_MEMORY_SCOPE_AGENT);
        }
      }
    }
    // ---- flag barrier: arrive (own line) -> block0 aggregates -> 8-line release
    if (p != 32){
      const unsigned tgt = (unsigned)(p + 1);
      __syncthreads();                        // drains vmcnt: h-stores ack'd
      if (tid == 0)
        __hip_atomic_store(&flags[bid * 16], tgt,
                           __ATOMIC_RELAXED, __HIP_MEMORY_SCOPE_AGENT);
      if (bid == 0){
        while (__hip_atomic_load(&flags[tid * 16],
                                 __ATOMIC_RELAXED, __HIP_MEMORY_SCOPE_AGENT) < tgt)
          __builtin_amdgcn_s_sleep(2);
        __syncthreads();
        if (tid < 8)
          __hip_atomic_store(&rel[tid * 16], tgt,
                             __ATOMIC_RELAXED, __HIP_MEMORY_SCOPE_AGENT);
      } else {
        if (tid == 0){
          while (__hip_atomic_load(&rel[(bid & 7) * 16],
                                   __ATOMIC_RELAXED, __HIP_MEMORY_SCOPE_AGENT) < tgt)
            __builtin_amdgcn_s_sleep(2);
        }
        __syncthreads();
      }
      asm volatile("" ::: "memory");          // forbid hoisting NT loads above spin
    }
  }
}

// ---------------------------------------------------- per-step LSTM (fallback)
template<int MODE>
__global__ void __launch_bounds__(64)
k_lstm2(const unsigned short* __restrict__ hA1, const unsigned short* __restrict__ hA2,
        const unsigned short* __restrict__ Wbf,
        const float* __restrict__ embg, const int* __restrict__ text,
        const float* __restrict__ b1sum,
        float* __restrict__ cstate, unsigned short* __restrict__ hout,
        unsigned short* __restrict__ h1r, int t){
  const int KS = MODE ? 32 : 16;
  const int wstr = MODE ? 1024 : 512;
  int m0 = blockIdx.x * 32, j0 = blockIdx.y * 16;
  int l = threadIdx.x, lr = l & 15, lk = l >> 4;
  v4f acc[2][4] = {};
  for (int ks = 0; ks < KS; ++ks){
    int kb = ks * 32 + lk * 8;
    const unsigned short* Ap = (MODE == 1 && ks >= 16) ? hA2 : hA1;
    int ka = (MODE == 1 && ks >= 16) ? (kb - 512) : kb;
    v8bf a0 = ld8(Ap + (size_t)(m0 + lr) * HID + ka);
    v8bf a1 = ld8(Ap + (size_t)(m0 + 16 + lr) * HID + ka);
#pragma unroll
    for (int g = 0; g < 4; ++g){
      v8bf bf = ld8(Wbf + (size_t)(g * HID + j0 + lr) * wstr + kb);
      acc[0][g] = __builtin_amdgcn_mfma_f32_16x16x32_bf16(a0, bf, acc[0][g], 0, 0, 0);
      acc[1][g] = __builtin_amdgcn_mfma_f32_16x16x32_bf16(a1, bf, acc[1][g], 0, 0, 0);
    }
  }
  int j = j0 + lr;
  float xi = 0.f, xf = 0.f, xg = 0.f, xo = 0.f;
  if (MODE == 1){
    xi = b1sum[j]; xf = b1sum[512 + j]; xg = b1sum[1024 + j]; xo = b1sum[1536 + j];
  }
#pragma unroll
  for (int fm = 0; fm < 2; ++fm){
#pragma unroll
    for (int r = 0; r < 4; ++r){
      int b = m0 + fm * 16 + lk * 4 + r;
      if (MODE == 0){
        const float* eg = embg + (size_t)text[b * T_ + t] * G4 + j;
        xi = eg[0]; xf = eg[512]; xg = eg[1024]; xo = eg[1536];
      }
      float ig = acc[fm][0][r] + xi, fg = acc[fm][1][r] + xf;
      float gg = acc[fm][2][r] + xg, og = acc[fm][3][r] + xo;
      size_t s = (size_t)b * HID + j;
      float cn = sigm(fg) * cstate[s] + sigm(ig) * tanh_f(gg);
      cstate[s] = cn;
      float hn = sigm(og) * tanh_f(cn);
      hout[s] = f2bf(hn);
      if (MODE == 1 && h1r != nullptr)
        h1r[((size_t)(t + 1) * B_ + b) * HID + j] = f2bf(hn);  // ring layout
    }
  }
}

// ----------------------------------------------------- batched attention ----
// Pass 1: S[t][l] = h1(t+1)[b] . fmapT[b][l]  (MFMA); sigmoid -> masks (d_out)
__global__ void __launch_bounds__(256)
k_attn1(const unsigned short* __restrict__ fT, const unsigned short* __restrict__ h1r,
        float* __restrict__ d_out){
  int b = blockIdx.x, tid = threadIdx.x, w = tid >> 6, l = tid & 63;
  int lr = l & 15, lk = l >> 4;
  const unsigned short* fb = fT + (size_t)b * L_ * HID;
  v4f acc[2][4] = {};
  for (int ks = 0; ks < 16; ++ks){
    int kb = ks * 32 + lk * 8;
    v8bf a0 = ld8(h1r + ((size_t)(lr + 1)  * B_ + b) * HID + kb);   // t = lr
    v8bf a1 = ld8(h1r + ((size_t)(lr + 17) * B_ + b) * HID + kb);   // t = 16+lr
#pragma unroll
    for (int fn = 0; fn < 4; ++fn){
      v8bf bf = ld8(fb + (size_t)(w * 64 + fn * 16 + lr) * HID + kb);
      acc[0][fn] = __builtin_amdgcn_mfma_f32_16x16x32_bf16(a0, bf, acc[0][fn], 0, 0, 0);
      acc[1][fn] = __builtin_amdgcn_mfma_f32_16x16x32_bf16(a1, bf, acc[1][fn], 0, 0, 0);
    }
  }
#pragma unroll
  for (int fm = 0; fm < 2; ++fm)
#pragma unroll
    for (int fn = 0; fn < 4; ++fn)
#pragma unroll
      for (int r = 0; r < 4; ++r){
        int tt = fm * 16 + lk * 4 + r;
        int li = w * 64 + fn * 16 + lr;
        d_out[MASK_OFF + ((size_t)b * T_ + tt) * L_ + li] = sigm(acc[fm][fn][r]);
      }
}

// Pass 2: C[t][ch] = sum_l A[t][l] * fmapT[b][l][ch]  (A staged from d_out masks)
__global__ void __launch_bounds__(512)
k_attn2(const unsigned short* __restrict__ fT, const float* __restrict__ d_out_ro,
        float* __restrict__ d_out, unsigned short* __restrict__ ctxbf){
  int b = blockIdx.x, tid = threadIdx.x, w = tid >> 6, l = tid & 63;
  __shared__ float aS[T_][L_];
  const float* ab = d_out_ro + MASK_OFF + (size_t)b * T_ * L_;
  for (int i = tid * 4; i < T_ * L_; i += 512 * 4){
    float4 v = *(const float4*)(ab + i);
    int tt = i >> 8, ll = i & 255;
    aS[tt][ll+0] = v.x; aS[tt][ll+1] = v.y; aS[tt][ll+2] = v.z; aS[tt][ll+3] = v.w;
  }
  __syncthreads();
  float acc[4][8] = {};
  const unsigned short* fb = fT + (size_t)b * L_ * HID + l * 8;
  for (int li = 0; li < L_; ++li){
    ushort4 u0 = *(const ushort4*)(fb + (size_t)li * HID);
    ushort4 u1 = *(const ushort4*)(fb + (size_t)li * HID + 4);
    float f[8] = {bf2f(u0.x), bf2f(u0.y), bf2f(u0.z), bf2f(u0.w),
                  bf2f(u1.x), bf2f(u1.y), bf2f(u1.z), bf2f(u1.w)};
#pragma unroll
    for (int tt = 0; tt < 4; ++tt){
      float a = aS[w * 4 + tt][li];
#pragma unroll
      for (int k = 0; k < 8; ++k) acc[tt][k] += a * f[k];
    }
  }
#pragma unroll
  for (int tt = 0; tt < 4; ++tt)
#pragma unroll
    for (int k = 0; k < 8; ++k){
      size_t o = ((size_t)b * T_ + w * 4 + tt) * HID + l * 8 + k;
      d_out[OH_OFF + o] = acc[tt][k];
      ctxbf[o] = f2bf(acc[tt][k]);
    }
}

// ------------------------------------------------------------------ final ---
__global__ void __launch_bounds__(256)
k_gen_m(const unsigned short* __restrict__ ctxbf, const unsigned short* __restrict__ genWbf,
        const float* __restrict__ genb, float* __restrict__ g){
  int m0 = blockIdx.x * 64 + (threadIdx.x >> 6) * 16;
  int j0 = blockIdx.y * 16;
  int l = threadIdx.x & 63, lr = l & 15, lk = l >> 4;
  int n = j0 + lr, nr = min(n, NC - 1);
  v4f acc = {0,0,0,0};
  for (int ks = 0; ks < 16; ++ks){
    int kb = ks * 32 + lk * 8;
    v8bf a  = ld8(ctxbf + (size_t)(m0 + lr) * HID + kb);
    v8bf bf = ld8(genWbf + (size_t)nr * HID + kb);
    acc = __builtin_amdgcn_mfma_f32_16x16x32_bf16(a, bf, acc, 0, 0, 0);
  }
  if (n < NC){
    float bb = genb[n];
#pragma unroll
    for (int r = 0; r < 4; ++r)
      g[(size_t)(m0 + lk * 4 + r) * NC + n] = acc[r] + bb;
  }
}

// --------------------------------------------------------------- fallbacks --
__global__ void __launch_bounds__(256)
k_attn_direct(const float* __restrict__ orig, const unsigned short* __restrict__ h1b,
              float* __restrict__ d_out, int t){
  int b = blockIdx.x, tid = threadIdx.x;
  __shared__ float h1s[HID];
  __shared__ float as[L_];
  h1s[tid]       = bf2f(h1b[(size_t)b * HID + tid]);
  h1s[256 + tid] = bf2f(h1b[(size_t)b * HID + 256 + tid]);
  __syncthreads();
  const float* fb = orig + (size_t)b * HID * L_;
  float dot = 0.f;
  for (int ch = 0; ch < HID; ++ch) dot += h1s[ch] * fb[(size_t)ch * L_ + tid];
  float a = sigm(dot);
  as[tid] = a;
  d_out[MASK_OFF + ((size_t)b * T_ + t) * L_ + tid] = a;
  __syncthreads();
  for (int cc = 0; cc < 2; ++cc){
    int ch = tid + cc * 256;
    float s = 0.f;
    for (int ll = 0; ll < L_; ++ll) s += as[ll] * fb[(size_t)ch * L_ + ll];
    d_out[OH_OFF + ((size_t)b * T_ + t) * HID + ch] = s;
  }
}

__global__ void k_gen_v(const float* __restrict__ ctx, const float* __restrict__ genW,
                        const float* __restrict__ genb, float* __restrict__ g){
  int o = blockIdx.x * 256 + threadIdx.x;
  if (o >= B_ * T_ * NC) return;
  int m = o / NC, n = o - m * NC;
  const float4* a = (const float4*)(ctx + (size_t)m * HID);
  const float4* wv = (const float4*)(genW + (size_t)n * HID);
  float s = genb[n];
  for (int k = 0; k < HID / 4; ++k){
    float4 av = a[k], w = wv[k];
    s += av.x * w.x + av.y * w.y + av.z * w.z + av.w * w.w;
  }
  g[o] = s;
}

// -----------------------------------------------------------------------------
extern "C" void kernel_launch(void* const* d_in, const int* in_sizes, int n_in,
                              void* d_out, int out_size, void* d_ws, size_t ws_size,
                              hipStream_t stream){
  const float* orig = (const float*)d_in[0];
  const int*   text = (const int*)  d_in[1];
  const float* embW = (const float*)d_in[2];
  const float* embb = (const float*)d_in[3];
  const float* Wih0 = (const float*)d_in[4];
  const float* Whh0 = (const float*)d_in[5];
  const float* bih0 = (const float*)d_in[6];
  const float* bhh0 = (const float*)d_in[7];
  const float* Wih1 = (const float*)d_in[8];
  const float* Whh1 = (const float*)d_in[9];
  const float* bih1 = (const float*)d_in[10];
  const float* bhh1 = (const float*)d_in[11];
  const float* genW = (const float*)d_in[12];
  const float* genb = (const float*)d_in[13];
  float* out = (float*)d_out;

  const size_t SLOTB = (size_t)B_ * HID * 2;          // ring slot bytes (256 KB)

  char* p = (char*)d_ws;
  float* embg  = (float*)p;           p += (size_t)NC * G4 * 4;
  float* b1sum = (float*)p;           p += (size_t)G4 * 4;
  // ---- zero-init region (h ping-pongs for fallback, flags, rel) ----
  unsigned short* h0p0 = (unsigned short*)p;   p += SLOTB;
  unsigned short* h0p1 = (unsigned short*)p;   p += SLOTB;
  unsigned short* h1p0 = (unsigned short*)p;   p += SLOTB;
  unsigned short* h1p1 = (unsigned short*)p;   p += SLOTB;
  unsigned int* flags = (unsigned int*)p;      p += 256 * 64;       // 1 line/block
  unsigned int* rel   = (unsigned int*)p;      p += 8 * 64;         // release lines
  size_t zbytes = (size_t)((char*)p - (char*)h0p0);
  // ---- end zero region ----
  unsigned short* Whh0bf  = (unsigned short*)p; p += (size_t)G4 * 512 * 2;
  unsigned short* Wcat1bf = (unsigned short*)p; p += (size_t)G4 * 1024 * 2;
  unsigned short* Wih0bf  = (unsigned short*)p; p += (size_t)G4 * 512 * 2;
  unsigned short* embXbf  = (unsigned short*)p; p += (size_t)NC * HID * 2;
  unsigned short* genWbf  = (unsigned short*)p; p += (size_t)NC * HID * 2;
  unsigned short* h0r = (unsigned short*)p;    p += 33 * SLOTB;     // 8.25 MB ring
  unsigned short* h1r = (unsigned short*)p;    p += 33 * SLOTB;     // 8.25 MB ring
  unsigned short* ctxbf = (unsigned short*)p;  p += (size_t)B_ * T_ * HID * 2;  // 8MB
  unsigned short* fmapT = (unsigned short*)p;  p += (size_t)B_ * L_ * HID * 2;  // 64MB
  bool big = ws_size >= (size_t)(p - (char*)d_ws);
  // fallback-only c-state aliases unused ring slots 4..7 of h0r
  float* c0 = (float*)(h0r + 4 * (size_t)B_ * HID);
  float* c1 = c0 + (size_t)B_ * HID;

  hipMemsetAsync(h0p0, 0, zbytes, stream);
  if (big){
    hipMemsetAsync(h0r, 0, SLOTB, stream);   // ring slot 0 = h0(0) = zeros
    hipMemsetAsync(h1r, 0, SLOTB, stream);   // ring slot 0 = h1(0) = zeros
  }

  k_wconv<<<(G4 * HID + 255) / 256, 256, 0, stream>>>(Whh0, Wih1, Whh1, Wih0,
                                                      Whh0bf, Wcat1bf, Wih0bf);
  k_small<<<(NC * HID + 255) / 256, 256, 0, stream>>>(embW, embb, genW, bih1, bhh1,
                                                      embXbf, genWbf, b1sum);
  k_embg_m<<<dim3(7, G4 / 16), 64, 0, stream>>>(embXbf, Wih0bf, bih0, bhh0, embg);
  if (big) k_fmapT<<<dim3(L_ / 32, HID / 32, B_), dim3(32, 8), 0, stream>>>(orig, fmapT);

  hipError_t ce = hipErrorUnknown;
  if (big){
    const unsigned short* a0 = Whh0bf; const unsigned short* a1 = Wcat1bf;
    const float* a2 = embg; const int* a3 = text; const float* a4 = b1sum;
    unsigned short* a5 = h0r; unsigned short* a6 = h1r;
    unsigned int* a7 = flags; unsigned int* a8 = rel;
    void* args[] = {&a0, &a1, &a2, &a3, &a4, &a5, &a6, &a7, &a8};
    ce = hipLaunchCooperativeKernel((const void*)k_loop, dim3(256), dim3(256),
                                    args, 0, stream);
  }
  if (ce != hipSuccess){
    // fallback: per-step kernels (ping-pong buffers; c-state aliases ring)
    if (big) hipMemsetAsync(c0, 0, (size_t)B_ * HID * 4 * 2, stream);
    unsigned short* h0bf[2] = {h0p0, h0p1};
    unsigned short* h1bf[2] = {h1p0, h1p1};
    for (int t = 0; t < T_; ++t){
      int ping = t & 1;
      k_lstm2<0><<<dim3(8, 32), 64, 0, stream>>>(h0bf[ping], nullptr, Whh0bf,
          embg, text, nullptr, c0, h0bf[ping ^ 1], nullptr, t);
      k_lstm2<1><<<dim3(8, 32), 64, 0, stream>>>(h0bf[ping ^ 1], h1bf[ping], Wcat1bf,
          nullptr, nullptr, b1sum, c1, h1bf[ping ^ 1], big ? h1r : nullptr, t);
      if (!big) k_attn_direct<<<B_, 256, 0, stream>>>(orig, h1bf[ping ^ 1], out, t);
    }
  }

  if (big){
    k_attn1<<<B_, 256, 0, stream>>>(fmapT, h1r, out);
    k_attn2<<<B_, 512, 0, stream>>>(fmapT, (const float*)out, out, ctxbf);
    k_gen_m<<<dim3(B_ * T_ / 64, 7), 256, 0, stream>>>(ctxbf, genWbf, genb, out);
  } else {
    k_gen_v<<<(B_ * T_ * NC + 255) / 256, 256, 0, stream>>>(out + OH_OFF, genW, genb, out);
  }
}